// Round 6
// baseline (729.893 us; speedup 1.0000x reference)
//
#include <hip/hip_runtime.h>

#define D_MODEL 768
#define D_STATE 16
#define D_INNER 1536
#define DT_RANK 48
#define NB 2
#define LSEQ 1024
#define NROWS (NB * LSEQ)

typedef __attribute__((ext_vector_type(4))) float f32x4;
typedef __attribute__((ext_vector_type(8))) short s16x8;
typedef __attribute__((ext_vector_type(8))) unsigned short u16x8;

__device__ __forceinline__ unsigned short f2bu(float f) {
  unsigned int x = __builtin_bit_cast(unsigned int, f);
  x += 0x7fffu + ((x >> 16) & 1u);
  return (unsigned short)(x >> 16);
}

// ---- staging: load 8 K-contiguous fp32, convert to bf16, zero-pad OOB ----
__device__ __forceinline__ void stage8(const float* src, bool vrow, int krem,
                                       unsigned short* dst) {
  u16x8 o;
  if (vrow && krem >= 8) {
    f32x4 v0 = *(const f32x4*)src;
    f32x4 v1 = *(const f32x4*)(src + 4);
#pragma unroll
    for (int j = 0; j < 4; j++) { o[j] = f2bu(v0[j]); o[4 + j] = f2bu(v1[j]); }
  } else {
#pragma unroll
    for (int j = 0; j < 8; j++) o[j] = f2bu((vrow && j < krem) ? src[j] : 0.0f);
  }
  *(u16x8*)dst = o;
}

// ---- C = A * B^T GEMM, bf16 MFMA, fp32 accum, fp32 output ----
// A: M x K (lda), B: N x K (ldb), C: M x N (ldc). 64x64x32 tiles, 4 waves.
__global__ __launch_bounds__(256) void gemm_bt(const float* __restrict__ A,
                                               const float* __restrict__ B,
                                               float* __restrict__ C, int M, int N, int K,
                                               int lda, int ldb, int ldc) {
  __shared__ __align__(16) unsigned short As[64][40];
  __shared__ __align__(16) unsigned short Bs[64][40];
  const int m0 = blockIdx.y * 64, n0 = blockIdx.x * 64;
  const int t = threadIdx.x;
  const int wave = t >> 6, lane = t & 63;
  const int wm = wave >> 1, wn = wave & 1;
  const int quad = lane >> 4, l16 = lane & 15;
  f32x4 acc[2][2] = {};
  const int srow = t >> 2;
  const int kseg = (t & 3) * 8;
  for (int k0 = 0; k0 < K; k0 += 32) {
    const int kk = k0 + kseg;
    stage8(A + (size_t)(m0 + srow) * lda + kk, (m0 + srow) < M, K - kk, &As[srow][kseg]);
    stage8(B + (size_t)(n0 + srow) * ldb + kk, (n0 + srow) < N, K - kk, &Bs[srow][kseg]);
    __syncthreads();
    s16x8 a0 = *(const s16x8*)&As[wm * 32 + l16][quad * 8];
    s16x8 a1 = *(const s16x8*)&As[wm * 32 + 16 + l16][quad * 8];
    s16x8 b0 = *(const s16x8*)&Bs[wn * 32 + l16][quad * 8];
    s16x8 b1 = *(const s16x8*)&Bs[wn * 32 + 16 + l16][quad * 8];
    acc[0][0] = __builtin_amdgcn_mfma_f32_16x16x32_bf16(a0, b0, acc[0][0], 0, 0, 0);
    acc[0][1] = __builtin_amdgcn_mfma_f32_16x16x32_bf16(a0, b1, acc[0][1], 0, 0, 0);
    acc[1][0] = __builtin_amdgcn_mfma_f32_16x16x32_bf16(a1, b0, acc[1][0], 0, 0, 0);
    acc[1][1] = __builtin_amdgcn_mfma_f32_16x16x32_bf16(a1, b1, acc[1][1], 0, 0, 0);
    __syncthreads();
  }
#pragma unroll
  for (int mi = 0; mi < 2; mi++)
#pragma unroll
    for (int ni = 0; ni < 2; ni++)
#pragma unroll
      for (int r = 0; r < 4; r++) {
        int row = m0 + wm * 32 + mi * 16 + quad * 4 + r;
        int col = n0 + wn * 32 + ni * 16 + l16;
        if (row < M && col < N) C[(size_t)row * ldc + col] = acc[mi][ni][r];
      }
}

// ---- causal depthwise conv (width 4, cross-correlation, left-pad 3) + SiLU ----
__global__ __launch_bounds__(256) void conv_silu_kernel(const float* __restrict__ xz,
                                                        const float* __restrict__ cw,
                                                        const float* __restrict__ cb,
                                                        float* __restrict__ xc) {
  int idx = blockIdx.x * 256 + threadIdx.x;
  if (idx >= NROWS * D_INNER) return;
  int c = idx % D_INNER;
  int row = idx / D_INNER;
  int l = row & (LSEQ - 1);
  float acc = cb[c];
#pragma unroll
  for (int j = 0; j < 4; j++) {
    int dl = l - 3 + j;
    if (dl >= 0) acc += xz[(size_t)(row - 3 + j) * 3072 + c] * cw[c * 4 + j];
  }
  float sg = 1.0f / (1.0f + expf(-acc));
  xc[idx] = acc * sg;
}

// ---- per (b,l): dt transform, closed-form rank-1 NS gamma, u' = gamma*dt*x ----
__global__ __launch_bounds__(256) void precompute_kernel(const float* __restrict__ xdbl,
                                                         float* __restrict__ dtbuf,
                                                         const float* __restrict__ xconv,
                                                         const float* __restrict__ dtb,
                                                         float* __restrict__ ubuf,
                                                         float* __restrict__ kqbuf) {
  int row = blockIdx.x;
  int t = threadIdx.x;
  const float* xr = xdbl + (size_t)row * 80;
  float nk = 0.0f;
#pragma unroll
  for (int n = 0; n < 16; n++) { float kv = xr[48 + n]; nk += kv * kv; }
  float dtf[6], u0[6];
  float nupart = 0.0f;
#pragma unroll
  for (int i = 0; i < 6; i++) {
    int d = i * 256 + t;
    float draw = dtbuf[(size_t)row * D_INNER + d] + dtb[d];
    float sg = 1.0f / (1.0f + expf(-draw));
    float dv = sg / (1.0f + sg * nk);
    dtf[i] = dv;
    float u = dv * xconv[(size_t)row * D_INNER + d];
    u0[i] = u;
    nupart += u * u;
  }
  __shared__ float red[4];
  float v = nupart;
#pragma unroll
  for (int off = 32; off > 0; off >>= 1) v += __shfl_xor(v, off);
  if ((t & 63) == 0) red[t >> 6] = v;
  __syncthreads();
  float nu = red[0] + red[1] + red[2] + red[3];
  float p = nu * nk;
  float s = sqrtf(p) + 1e-7f;
  float tt = p / (s * s);
  float gamma = (3.4445f + tt * (-4.7750f + 2.0315f * tt)) / s;
#pragma unroll
  for (int i = 0; i < 6; i++) {
    int d = i * 256 + t;
    dtbuf[(size_t)row * D_INNER + d] = dtf[i];
    ubuf[(size_t)row * D_INNER + d] = gamma * u0[i];
  }
  if (t < 16) {
    kqbuf[(size_t)row * 32 + t] = xr[48 + t];       // k
    kqbuf[(size_t)row * 32 + 16 + t] = xr[64 + t];  // q
  }
}

// ---- sequential scan: 4 threads per (b,d), 4 n-states each, 8-deep prefetch ----
#define PF 8
__global__ __launch_bounds__(64) void scan_kernel(const float* __restrict__ ubuf,
                                                  const float* __restrict__ dtbuf,
                                                  const float* __restrict__ kqbuf,
                                                  float* __restrict__ ybuf) {
  int g = blockIdx.x * 64 + threadIdx.x;
  int nq = g & 3;
  int drow = g >> 2;
  int b = drow / D_INNER;
  int d = drow % D_INNER;
  const size_t base = (size_t)b * LSEQ * D_INNER + d;
  const float* up_p = ubuf + base;
  const float* dt_p = dtbuf + base;
  const float* kq_p = kqbuf + (size_t)b * LSEQ * 32 + nq * 4;
  float* y_p = ybuf + base;
  float v[4] = {0.f, 0.f, 0.f, 0.f}, h[4] = {0.f, 0.f, 0.f, 0.f};
  float up_r[PF], dt_r[PF];
  f32x4 kv_r[PF], qv_r[PF];
#pragma unroll
  for (int i = 0; i < PF; i++) {
    size_t o = (size_t)i * D_INNER;
    up_r[i] = up_p[o];
    dt_r[i] = dt_p[o];
    kv_r[i] = *(const f32x4*)(kq_p + (size_t)i * 32);
    qv_r[i] = *(const f32x4*)(kq_p + (size_t)i * 32 + 16);
  }
  for (int t0 = 0; t0 < LSEQ; t0 += PF) {
#pragma unroll
    for (int ph = 0; ph < PF; ph++) {
      const int tstep = t0 + ph;
      const float up = up_r[ph], dtf = dt_r[ph];
      const f32x4 kv = kv_r[ph], qv = qv_r[ph];
      if (tstep + PF < LSEQ) {
        size_t o = (size_t)(tstep + PF) * D_INNER;
        up_r[ph] = up_p[o];
        dt_r[ph] = dt_p[o];
        kv_r[ph] = *(const f32x4*)(kq_p + (size_t)(tstep + PF) * 32);
        qv_r[ph] = *(const f32x4*)(kq_p + (size_t)(tstep + PF) * 32 + 16);
      }
      float yp = 0.0f;
#pragma unroll
      for (int j = 0; j < 4; j++) {
        float kj = kv[j];
        v[j] = fmaf(0.9f, v[j], up * kj);              // v = beta*v + alpha*NS (rank-1)
        float dA = fmaf(-dtf * kj, kj, 1.0f);          // 1 - dt*k^2
        h[j] = fmaf(dA, h[j], v[j]);                   // h = dA*h + v
        yp = fmaf(h[j], qv[j], yp);                    // y += h*q
      }
      yp += __shfl_xor(yp, 1);
      yp += __shfl_xor(yp, 2);
      if (nq == 0) y_p[(size_t)tstep * D_INNER] = yp;
    }
  }
}

// ---- gate: yg = (y_scan + D*xconv) * silu(z) ----
__global__ __launch_bounds__(256) void gate_kernel(const float* __restrict__ ybuf,
                                                   const float* __restrict__ xconv,
                                                   const float* __restrict__ xz,
                                                   const float* __restrict__ Dp,
                                                   float* __restrict__ yg) {
  int idx = blockIdx.x * 256 + threadIdx.x;
  if (idx >= NROWS * D_INNER) return;
  int c = idx % D_INNER;
  int row = idx / D_INNER;
  float z = xz[(size_t)row * 3072 + 1536 + c];
  float sz = z / (1.0f + expf(-z));
  yg[idx] = (ybuf[idx] + Dp[c] * xconv[idx]) * sz;
}

extern "C" void kernel_launch(void* const* d_in, const int* in_sizes, int n_in,
                              void* d_out, int out_size, void* d_ws, size_t ws_size,
                              hipStream_t stream) {
  const float* hidden = (const float*)d_in[0];
  const float* w_in   = (const float*)d_in[1];
  const float* conv_w = (const float*)d_in[2];
  const float* conv_b = (const float*)d_in[3];
  const float* w_x    = (const float*)d_in[4];
  const float* w_dt   = (const float*)d_in[5];
  const float* b_dt   = (const float*)d_in[6];
  const float* w_out  = (const float*)d_in[7];
  const float* Dp     = (const float*)d_in[8];

  float* ws    = (float*)d_ws;
  float* xz    = ws;                                  // 2048*3072
  float* xconv = xz + (size_t)NROWS * 3072;           // 2048*1536
  float* xdbl  = xconv + (size_t)NROWS * D_INNER;     // 2048*80
  float* dtbuf = xdbl + (size_t)NROWS * 80;           // 2048*1536
  float* ubuf  = dtbuf + (size_t)NROWS * D_INNER;     // 2048*1536
  float* kqbuf = ubuf + (size_t)NROWS * D_INNER;      // 2048*32
  float* ybuf  = kqbuf + (size_t)NROWS * 32;          // 2048*1536
  float* yg    = ubuf;                                // reuse after scan

  dim3 blk(256);
  // 1. in_proj: xz = hidden @ W_in^T  (2048 x 3072, K=768)
  gemm_bt<<<dim3(48, 32), blk, 0, stream>>>(hidden, w_in, xz, 2048, 3072, 768, 768, 768, 3072);
  // 2. causal conv + SiLU
  conv_silu_kernel<<<dim3(12288), blk, 0, stream>>>(xz, conv_w, conv_b, xconv);
  // 3. x_proj: xdbl = xconv @ W_x^T  (2048 x 80, K=1536)
  gemm_bt<<<dim3(2, 32), blk, 0, stream>>>(xconv, w_x, xdbl, 2048, 80, 1536, 1536, 1536, 80);
  // 4. dt_head: dt_raw = dt_low @ W_dt^T  (2048 x 1536, K=48, lda=80)
  gemm_bt<<<dim3(24, 32), blk, 0, stream>>>(xdbl, w_dt, dtbuf, 2048, 1536, 48, 80, 48, 1536);
  // 5. precompute dt-final, gamma, u', k, q
  precompute_kernel<<<dim3(NROWS), blk, 0, stream>>>(xdbl, dtbuf, xconv, b_dt, ubuf, kqbuf);
  // 6. sequential scan over L
  scan_kernel<<<dim3(192), dim3(64), 0, stream>>>(ubuf, dtbuf, kqbuf, ybuf);
  // 7. gate
  gate_kernel<<<dim3(12288), blk, 0, stream>>>(ybuf, xconv, xz, Dp, yg);
  // 8. out_proj -> FP32 d_out  (2048 x 768, K=1536)
  gemm_bt<<<dim3(12, 32), blk, 0, stream>>>(yg, w_out, (float*)d_out, 2048, 768, 1536,
                                            1536, 1536, 768);
}

// Round 7
// 401.106 us; speedup vs baseline: 1.8197x; 1.8197x over previous
//
#include <hip/hip_runtime.h>

#define D_MODEL 768
#define D_STATE 16
#define D_INNER 1536
#define DT_RANK 48
#define NB 2
#define LSEQ 1024
#define NROWS (NB * LSEQ)

typedef __attribute__((ext_vector_type(4))) float f32x4;
typedef __attribute__((ext_vector_type(8))) short s16x8;
typedef __attribute__((ext_vector_type(8))) unsigned short u16x8;

__device__ __forceinline__ unsigned short f2bu(float f) {
  unsigned int x = __builtin_bit_cast(unsigned int, f);
  x += 0x7fffu + ((x >> 16) & 1u);
  return (unsigned short)(x >> 16);
}

// ---- staging: load 8 K-contiguous fp32, convert to bf16, zero-pad OOB ----
__device__ __forceinline__ void stage8(const float* src, bool vrow, int krem,
                                       unsigned short* dst) {
  u16x8 o;
  if (vrow && krem >= 8) {
    f32x4 v0 = *(const f32x4*)src;
    f32x4 v1 = *(const f32x4*)(src + 4);
#pragma unroll
    for (int j = 0; j < 4; j++) { o[j] = f2bu(v0[j]); o[4 + j] = f2bu(v1[j]); }
  } else {
#pragma unroll
    for (int j = 0; j < 8; j++) o[j] = f2bu((vrow && j < krem) ? src[j] : 0.0f);
  }
  *(u16x8*)dst = o;
}

// ---- C = A * B^T GEMM, bf16 MFMA, fp32 accum, fp32 output ----
__global__ __launch_bounds__(256) void gemm_bt(const float* __restrict__ A,
                                               const float* __restrict__ B,
                                               float* __restrict__ C, int M, int N, int K,
                                               int lda, int ldb, int ldc) {
  __shared__ __align__(16) unsigned short As[64][40];
  __shared__ __align__(16) unsigned short Bs[64][40];
  const int m0 = blockIdx.y * 64, n0 = blockIdx.x * 64;
  const int t = threadIdx.x;
  const int wave = t >> 6, lane = t & 63;
  const int wm = wave >> 1, wn = wave & 1;
  const int quad = lane >> 4, l16 = lane & 15;
  f32x4 acc[2][2] = {};
  const int srow = t >> 2;
  const int kseg = (t & 3) * 8;
  for (int k0 = 0; k0 < K; k0 += 32) {
    const int kk = k0 + kseg;
    stage8(A + (size_t)(m0 + srow) * lda + kk, (m0 + srow) < M, K - kk, &As[srow][kseg]);
    stage8(B + (size_t)(n0 + srow) * ldb + kk, (n0 + srow) < N, K - kk, &Bs[srow][kseg]);
    __syncthreads();
    s16x8 a0 = *(const s16x8*)&As[wm * 32 + l16][quad * 8];
    s16x8 a1 = *(const s16x8*)&As[wm * 32 + 16 + l16][quad * 8];
    s16x8 b0 = *(const s16x8*)&Bs[wn * 32 + l16][quad * 8];
    s16x8 b1 = *(const s16x8*)&Bs[wn * 32 + 16 + l16][quad * 8];
    acc[0][0] = __builtin_amdgcn_mfma_f32_16x16x32_bf16(a0, b0, acc[0][0], 0, 0, 0);
    acc[0][1] = __builtin_amdgcn_mfma_f32_16x16x32_bf16(a0, b1, acc[0][1], 0, 0, 0);
    acc[1][0] = __builtin_amdgcn_mfma_f32_16x16x32_bf16(a1, b0, acc[1][0], 0, 0, 0);
    acc[1][1] = __builtin_amdgcn_mfma_f32_16x16x32_bf16(a1, b1, acc[1][1], 0, 0, 0);
    __syncthreads();
  }
#pragma unroll
  for (int mi = 0; mi < 2; mi++)
#pragma unroll
    for (int ni = 0; ni < 2; ni++)
#pragma unroll
      for (int r = 0; r < 4; r++) {
        int row = m0 + wm * 32 + mi * 16 + quad * 4 + r;
        int col = n0 + wn * 32 + ni * 16 + l16;
        if (row < M && col < N) C[(size_t)row * ldc + col] = acc[mi][ni][r];
      }
}

// ---- causal depthwise conv (width 4) + SiLU ----
__global__ __launch_bounds__(256) void conv_silu_kernel(const float* __restrict__ xz,
                                                        const float* __restrict__ cw,
                                                        const float* __restrict__ cb,
                                                        float* __restrict__ xc) {
  int idx = blockIdx.x * 256 + threadIdx.x;
  if (idx >= NROWS * D_INNER) return;
  int c = idx % D_INNER;
  int row = idx / D_INNER;
  int l = row & (LSEQ - 1);
  float acc = cb[c];
#pragma unroll
  for (int j = 0; j < 4; j++) {
    int dl = l - 3 + j;
    if (dl >= 0) acc += xz[(size_t)(row - 3 + j) * 3072 + c] * cw[c * 4 + j];
  }
  float sg = 1.0f / (1.0f + expf(-acc));
  xc[idx] = acc * sg;
}

// ---- per (b,l): dt transform, closed-form rank-1 NS gamma, u' = gamma*dt*x ----
__global__ __launch_bounds__(256) void precompute_kernel(const float* __restrict__ xdbl,
                                                         float* __restrict__ dtbuf,
                                                         const float* __restrict__ xconv,
                                                         const float* __restrict__ dtb,
                                                         float* __restrict__ ubuf,
                                                         float* __restrict__ kqbuf) {
  int row = blockIdx.x;
  int t = threadIdx.x;
  const float* xr = xdbl + (size_t)row * 80;
  float nk = 0.0f;
#pragma unroll
  for (int n = 0; n < 16; n++) { float kv = xr[48 + n]; nk += kv * kv; }
  float dtf[6], u0[6];
  float nupart = 0.0f;
#pragma unroll
  for (int i = 0; i < 6; i++) {
    int d = i * 256 + t;
    float draw = dtbuf[(size_t)row * D_INNER + d] + dtb[d];
    float sg = 1.0f / (1.0f + expf(-draw));
    float dv = sg / (1.0f + sg * nk);
    dtf[i] = dv;
    float u = dv * xconv[(size_t)row * D_INNER + d];
    u0[i] = u;
    nupart += u * u;
  }
  __shared__ float red[4];
  float v = nupart;
#pragma unroll
  for (int off = 32; off > 0; off >>= 1) v += __shfl_xor(v, off);
  if ((t & 63) == 0) red[t >> 6] = v;
  __syncthreads();
  float nu = red[0] + red[1] + red[2] + red[3];
  float p = nu * nk;
  float s = sqrtf(p) + 1e-7f;
  float tt = p / (s * s);
  float gamma = (3.4445f + tt * (-4.7750f + 2.0315f * tt)) / s;
#pragma unroll
  for (int i = 0; i < 6; i++) {
    int d = i * 256 + t;
    dtbuf[(size_t)row * D_INNER + d] = dtf[i];
    ubuf[(size_t)row * D_INNER + d] = gamma * u0[i];
  }
  if (t < 16) {
    kqbuf[(size_t)row * 32 + t] = xr[48 + t];       // k
    kqbuf[(size_t)row * 32 + 16 + t] = xr[64 + t];  // q
  }
}

// ---- scan: 1 wave per 16 d, double-buffered LDS tiles of 32 steps ----
// block = 64 thr = 16 d x 4 nq. Global loads -> 32 regs -> LDS; inner loop LDS-only.
__global__ __launch_bounds__(64, 1) void scan_kernel(const float* __restrict__ ubuf,
                                                     const float* __restrict__ dtbuf,
                                                     const float* __restrict__ kqbuf,
                                                     float* __restrict__ ybuf) {
  __shared__ float u_s[2][32][16];
  __shared__ float dt_s[2][32][16];
  __shared__ __align__(16) float kq_s[2][32][32];
  const int t = threadIdx.x;
  const int nq = t & 3;
  const int dloc = t >> 2;
  const int b = blockIdx.x / 96;           // 192 blocks: 2 b x 96
  const int d0 = (blockIdx.x % 96) * 16;
  const size_t ub = (size_t)b * LSEQ * D_INNER + d0;
  const float* kqb = kqbuf + (size_t)b * LSEQ * 32;
  float* y_p = ybuf + (size_t)b * LSEQ * D_INNER + d0 + dloc;

  const int scol = t & 15, srow0 = t >> 4;       // u/dt staging role
  const int krow0 = t >> 3, kcol = (t & 7) * 4;  // kq staging role

  float pu[8], pd[8];
  f32x4 pk[4];
  auto prefetch = [&](int t0) {
#pragma unroll
    for (int i = 0; i < 8; i++) {
      size_t off = ub + (size_t)(t0 + srow0 + 4 * i) * D_INNER + scol;
      pu[i] = ubuf[off];
      pd[i] = dtbuf[off];
    }
#pragma unroll
    for (int i = 0; i < 4; i++)
      pk[i] = *(const f32x4*)(kqb + (size_t)(t0 + krow0 + 8 * i) * 32 + kcol);
  };
  auto writelds = [&](int bi) {
#pragma unroll
    for (int i = 0; i < 8; i++) {
      u_s[bi][srow0 + 4 * i][scol] = pu[i];
      dt_s[bi][srow0 + 4 * i][scol] = pd[i];
    }
#pragma unroll
    for (int i = 0; i < 4; i++)
      *(f32x4*)&kq_s[bi][krow0 + 8 * i][kcol] = pk[i];
  };

  float v[4] = {0.f, 0.f, 0.f, 0.f}, h[4] = {0.f, 0.f, 0.f, 0.f};
  prefetch(0);
  writelds(0);
  int buf = 0;
  for (int t0 = 0; t0 < LSEQ; t0 += 32) {
    const bool more = (t0 + 32 < LSEQ);
    if (more) prefetch(t0 + 32);  // loads in flight across the 32-step compute
#pragma unroll 4
    for (int s = 0; s < 32; s++) {
      float u = u_s[buf][s][dloc];
      float dtf = dt_s[buf][s][dloc];
      f32x4 kv = *(const f32x4*)&kq_s[buf][s][nq * 4];
      f32x4 qv = *(const f32x4*)&kq_s[buf][s][16 + nq * 4];
      float yp = 0.0f;
#pragma unroll
      for (int j = 0; j < 4; j++) {
        float kj = kv[j];
        v[j] = fmaf(0.9f, v[j], u * kj);             // v = beta*v + alpha*NS (rank-1)
        float dA = fmaf(-dtf * kj, kj, 1.0f);        // 1 - dt*k^2
        h[j] = fmaf(dA, h[j], v[j]);                 // h = dA*h + v
        yp = fmaf(h[j], qv[j], yp);                  // y += h*q
      }
      yp += __shfl_xor(yp, 1);
      yp += __shfl_xor(yp, 2);
      if (nq == 0) y_p[(size_t)(t0 + s) * D_INNER] = yp;
    }
    if (more) writelds(buf ^ 1);  // vmcnt drained here, after compute
    buf ^= 1;
  }
}

// ---- gate: yg = (y_scan + D*xconv) * silu(z) ----
__global__ __launch_bounds__(256) void gate_kernel(const float* __restrict__ ybuf,
                                                   const float* __restrict__ xconv,
                                                   const float* __restrict__ xz,
                                                   const float* __restrict__ Dp,
                                                   float* __restrict__ yg) {
  int idx = blockIdx.x * 256 + threadIdx.x;
  if (idx >= NROWS * D_INNER) return;
  int c = idx % D_INNER;
  int row = idx / D_INNER;
  float z = xz[(size_t)row * 3072 + 1536 + c];
  float sz = z / (1.0f + expf(-z));
  yg[idx] = (ybuf[idx] + Dp[c] * xconv[idx]) * sz;
}

extern "C" void kernel_launch(void* const* d_in, const int* in_sizes, int n_in,
                              void* d_out, int out_size, void* d_ws, size_t ws_size,
                              hipStream_t stream) {
  const float* hidden = (const float*)d_in[0];
  const float* w_in   = (const float*)d_in[1];
  const float* conv_w = (const float*)d_in[2];
  const float* conv_b = (const float*)d_in[3];
  const float* w_x    = (const float*)d_in[4];
  const float* w_dt   = (const float*)d_in[5];
  const float* b_dt   = (const float*)d_in[6];
  const float* w_out  = (const float*)d_in[7];
  const float* Dp     = (const float*)d_in[8];

  float* ws    = (float*)d_ws;
  float* xz    = ws;                                  // 2048*3072
  float* xconv = xz + (size_t)NROWS * 3072;           // 2048*1536
  float* xdbl  = xconv + (size_t)NROWS * D_INNER;     // 2048*80
  float* dtbuf = xdbl + (size_t)NROWS * 80;           // 2048*1536
  float* ubuf  = dtbuf + (size_t)NROWS * D_INNER;     // 2048*1536
  float* kqbuf = ubuf + (size_t)NROWS * D_INNER;      // 2048*32
  float* ybuf  = kqbuf + (size_t)NROWS * 32;          // 2048*1536
  float* yg    = ubuf;                                // reuse after scan

  dim3 blk(256);
  // 1. in_proj: xz = hidden @ W_in^T  (2048 x 3072, K=768)
  gemm_bt<<<dim3(48, 32), blk, 0, stream>>>(hidden, w_in, xz, 2048, 3072, 768, 768, 768, 3072);
  // 2. causal conv + SiLU
  conv_silu_kernel<<<dim3(12288), blk, 0, stream>>>(xz, conv_w, conv_b, xconv);
  // 3. x_proj: xdbl = xconv @ W_x^T  (2048 x 80, K=1536)
  gemm_bt<<<dim3(2, 32), blk, 0, stream>>>(xconv, w_x, xdbl, 2048, 80, 1536, 1536, 1536, 80);
  // 4. dt_head: dt_raw = dt_low @ W_dt^T  (2048 x 1536, K=48, lda=80)
  gemm_bt<<<dim3(24, 32), blk, 0, stream>>>(xdbl, w_dt, dtbuf, 2048, 1536, 48, 80, 48, 1536);
  // 5. precompute dt-final, gamma, u', k, q
  precompute_kernel<<<dim3(NROWS), blk, 0, stream>>>(xdbl, dtbuf, xconv, b_dt, ubuf, kqbuf);
  // 6. sequential scan over L (192 blocks x 1 wave, LDS double-buffered)
  scan_kernel<<<dim3(192), dim3(64), 0, stream>>>(ubuf, dtbuf, kqbuf, ybuf);
  // 7. gate
  gate_kernel<<<dim3(12288), blk, 0, stream>>>(ybuf, xconv, xz, Dp, yg);
  // 8. out_proj -> FP32 d_out  (2048 x 768, K=1536)
  gemm_bt<<<dim3(12, 32), blk, 0, stream>>>(yg, w_out, (float*)d_out, 2048, 768, 1536,
                                            1536, 1536, 768);
}

// Round 8
// 295.760 us; speedup vs baseline: 2.4679x; 1.3562x over previous
//
#include <hip/hip_runtime.h>

#define D_MODEL 768
#define D_STATE 16
#define D_INNER 1536
#define DT_RANK 48
#define NB 2
#define LSEQ 1024
#define NROWS (NB * LSEQ)
#define CCH 8                  // chunks over L
#define CLEN (LSEQ / CCH)      // 128 steps per chunk
#define BETA_CL 1.3900845e-06f // 0.9^128

typedef __attribute__((ext_vector_type(4))) float f32x4;
typedef __attribute__((ext_vector_type(8))) short s16x8;
typedef __attribute__((ext_vector_type(8))) unsigned short u16x8;

__device__ __forceinline__ unsigned short f2bu(float f) {
  unsigned int x = __builtin_bit_cast(unsigned int, f);
  x += 0x7fffu + ((x >> 16) & 1u);
  return (unsigned short)(x >> 16);
}

// ---- staging: load 8 K-contiguous fp32, convert to bf16, zero-pad OOB ----
__device__ __forceinline__ void stage8(const float* src, bool vrow, int krem,
                                       unsigned short* dst) {
  u16x8 o;
  if (vrow && krem >= 8) {
    f32x4 v0 = *(const f32x4*)src;
    f32x4 v1 = *(const f32x4*)(src + 4);
#pragma unroll
    for (int j = 0; j < 4; j++) { o[j] = f2bu(v0[j]); o[4 + j] = f2bu(v1[j]); }
  } else {
#pragma unroll
    for (int j = 0; j < 8; j++) o[j] = f2bu((vrow && j < krem) ? src[j] : 0.0f);
  }
  *(u16x8*)dst = o;
}

// ---- C = A * B^T GEMM, bf16 MFMA, fp32 accum, fp32 output ----
__global__ __launch_bounds__(256) void gemm_bt(const float* __restrict__ A,
                                               const float* __restrict__ B,
                                               float* __restrict__ C, int M, int N, int K,
                                               int lda, int ldb, int ldc) {
  __shared__ __align__(16) unsigned short As[64][40];
  __shared__ __align__(16) unsigned short Bs[64][40];
  const int m0 = blockIdx.y * 64, n0 = blockIdx.x * 64;
  const int t = threadIdx.x;
  const int wave = t >> 6, lane = t & 63;
  const int wm = wave >> 1, wn = wave & 1;
  const int quad = lane >> 4, l16 = lane & 15;
  f32x4 acc[2][2] = {};
  const int srow = t >> 2;
  const int kseg = (t & 3) * 8;
  for (int k0 = 0; k0 < K; k0 += 32) {
    const int kk = k0 + kseg;
    stage8(A + (size_t)(m0 + srow) * lda + kk, (m0 + srow) < M, K - kk, &As[srow][kseg]);
    stage8(B + (size_t)(n0 + srow) * ldb + kk, (n0 + srow) < N, K - kk, &Bs[srow][kseg]);
    __syncthreads();
    s16x8 a0 = *(const s16x8*)&As[wm * 32 + l16][quad * 8];
    s16x8 a1 = *(const s16x8*)&As[wm * 32 + 16 + l16][quad * 8];
    s16x8 b0 = *(const s16x8*)&Bs[wn * 32 + l16][quad * 8];
    s16x8 b1 = *(const s16x8*)&Bs[wn * 32 + 16 + l16][quad * 8];
    acc[0][0] = __builtin_amdgcn_mfma_f32_16x16x32_bf16(a0, b0, acc[0][0], 0, 0, 0);
    acc[0][1] = __builtin_amdgcn_mfma_f32_16x16x32_bf16(a0, b1, acc[0][1], 0, 0, 0);
    acc[1][0] = __builtin_amdgcn_mfma_f32_16x16x32_bf16(a1, b0, acc[1][0], 0, 0, 0);
    acc[1][1] = __builtin_amdgcn_mfma_f32_16x16x32_bf16(a1, b1, acc[1][1], 0, 0, 0);
    __syncthreads();
  }
#pragma unroll
  for (int mi = 0; mi < 2; mi++)
#pragma unroll
    for (int ni = 0; ni < 2; ni++)
#pragma unroll
      for (int r = 0; r < 4; r++) {
        int row = m0 + wm * 32 + mi * 16 + quad * 4 + r;
        int col = n0 + wn * 32 + ni * 16 + l16;
        if (row < M && col < N) C[(size_t)row * ldc + col] = acc[mi][ni][r];
      }
}

// ---- causal depthwise conv (width 4) + SiLU ----
__global__ __launch_bounds__(256) void conv_silu_kernel(const float* __restrict__ xz,
                                                        const float* __restrict__ cw,
                                                        const float* __restrict__ cb,
                                                        float* __restrict__ xc) {
  int idx = blockIdx.x * 256 + threadIdx.x;
  if (idx >= NROWS * D_INNER) return;
  int c = idx % D_INNER;
  int row = idx / D_INNER;
  int l = row & (LSEQ - 1);
  float acc = cb[c];
#pragma unroll
  for (int j = 0; j < 4; j++) {
    int dl = l - 3 + j;
    if (dl >= 0) acc += xz[(size_t)(row - 3 + j) * 3072 + c] * cw[c * 4 + j];
  }
  float sg = 1.0f / (1.0f + expf(-acc));
  xc[idx] = acc * sg;
}

// ---- per (b,l): dt transform, closed-form rank-1 NS gamma, u' = gamma*dt*x ----
__global__ __launch_bounds__(256) void precompute_kernel(const float* __restrict__ xdbl,
                                                         float* __restrict__ dtbuf,
                                                         const float* __restrict__ xconv,
                                                         const float* __restrict__ dtb,
                                                         float* __restrict__ ubuf,
                                                         float* __restrict__ kqbuf) {
  int row = blockIdx.x;
  int t = threadIdx.x;
  const float* xr = xdbl + (size_t)row * 80;
  float nk = 0.0f;
#pragma unroll
  for (int n = 0; n < 16; n++) { float kv = xr[48 + n]; nk += kv * kv; }
  float dtf[6], u0[6];
  float nupart = 0.0f;
#pragma unroll
  for (int i = 0; i < 6; i++) {
    int d = i * 256 + t;
    float draw = dtbuf[(size_t)row * D_INNER + d] + dtb[d];
    float sg = 1.0f / (1.0f + expf(-draw));
    float dv = sg / (1.0f + sg * nk);
    dtf[i] = dv;
    float u = dv * xconv[(size_t)row * D_INNER + d];
    u0[i] = u;
    nupart += u * u;
  }
  __shared__ float red[4];
  float v = nupart;
#pragma unroll
  for (int off = 32; off > 0; off >>= 1) v += __shfl_xor(v, off);
  if ((t & 63) == 0) red[t >> 6] = v;
  __syncthreads();
  float nu = red[0] + red[1] + red[2] + red[3];
  float p = nu * nk;
  float s = sqrtf(p) + 1e-7f;
  float tt = p / (s * s);
  float gamma = (3.4445f + tt * (-4.7750f + 2.0315f * tt)) / s;
#pragma unroll
  for (int i = 0; i < 6; i++) {
    int d = i * 256 + t;
    dtbuf[(size_t)row * D_INNER + d] = dtf[i];
    ubuf[(size_t)row * D_INNER + d] = gamma * u0[i];
  }
  if (t < 16) {
    kqbuf[(size_t)row * 32 + t] = xr[48 + t];       // k
    kqbuf[(size_t)row * 32 + 16 + t] = xr[64 + t];  // q
  }
}

// ================= segmented scan =================
// state s=(v,h): v_t = B v_{t-1} + w_t ; h_t = a_t h_{t-1} + v_t.
// chunk transfer: s_end = [[B^CL,0],[g,r]] s_0 + (cv,ch).

// phase 1: per chunk from zero state -> cv, ch, g, r   (no y, no shuffles)
__global__ __launch_bounds__(64) void scan_phase1(const float* __restrict__ ubuf,
                                                  const float* __restrict__ dtbuf,
                                                  const float* __restrict__ kqbuf,
                                                  float* __restrict__ cvp,
                                                  float* __restrict__ chp,
                                                  float* __restrict__ gp,
                                                  float* __restrict__ rp) {
  __shared__ float u_s[2][32][16];
  __shared__ float dt_s[2][32][16];
  __shared__ __align__(16) float kq_s[2][32][32];
  const int t = threadIdx.x;
  const int nq = t & 3, dloc = t >> 2;
  const int b = blockIdx.x / (96 * CCH);
  const int rem = blockIdx.x % (96 * CCH);
  const int d0 = (rem / CCH) * 16;
  const int c = rem % CCH;
  const int tbase = c * CLEN;
  const size_t ub = (size_t)b * LSEQ * D_INNER + d0;
  const float* kqb = kqbuf + (size_t)b * LSEQ * 32;
  const int scol = t & 15, srow0 = t >> 4;
  const int krow0 = t >> 3, kcol = (t & 7) * 4;
  float pu[8], pd[8];
  f32x4 pk[4];
  auto prefetch = [&](int t0) {
#pragma unroll
    for (int i = 0; i < 8; i++) {
      size_t off = ub + (size_t)(t0 + srow0 + 4 * i) * D_INNER + scol;
      pu[i] = ubuf[off];
      pd[i] = dtbuf[off];
    }
#pragma unroll
    for (int i = 0; i < 4; i++)
      pk[i] = *(const f32x4*)(kqb + (size_t)(t0 + krow0 + 8 * i) * 32 + kcol);
  };
  auto writelds = [&](int bi) {
#pragma unroll
    for (int i = 0; i < 8; i++) {
      u_s[bi][srow0 + 4 * i][scol] = pu[i];
      dt_s[bi][srow0 + 4 * i][scol] = pd[i];
    }
#pragma unroll
    for (int i = 0; i < 4; i++)
      *(f32x4*)&kq_s[bi][krow0 + 8 * i][kcol] = pk[i];
  };
  f32x4 v = {0.f, 0.f, 0.f, 0.f}, h = {0.f, 0.f, 0.f, 0.f};
  f32x4 g = {0.f, 0.f, 0.f, 0.f}, r = {1.f, 1.f, 1.f, 1.f};
  float bt = 0.9f;
  prefetch(tbase);
  writelds(0);
  int buf = 0;
  for (int t0 = 0; t0 < CLEN; t0 += 32) {
    const bool more = (t0 + 32 < CLEN);
    if (more) prefetch(tbase + t0 + 32);
#pragma unroll 4
    for (int s = 0; s < 32; s++) {
      float u = u_s[buf][s][dloc];
      float dtf = dt_s[buf][s][dloc];
      f32x4 kv = *(const f32x4*)&kq_s[buf][s][nq * 4];
#pragma unroll
      for (int j = 0; j < 4; j++) {
        float kj = kv[j];
        v[j] = fmaf(0.9f, v[j], u * kj);
        float a = fmaf(-dtf * kj, kj, 1.0f);
        h[j] = fmaf(a, h[j], v[j]);
        r[j] *= a;
        g[j] = fmaf(a, g[j], bt);
      }
      bt *= 0.9f;
    }
    if (more) writelds(buf ^ 1);
    buf ^= 1;
  }
  size_t o = (((size_t)b * CCH + c) * D_INNER + d0 + dloc) * 16 + nq * 4;
  *(f32x4*)(cvp + o) = v;
  *(f32x4*)(chp + o) = h;
  *(f32x4*)(gp + o) = g;
  *(f32x4*)(rp + o) = r;
}

// phase 2: compose chunk transfers -> per-chunk initial state, in-place over g/r
__global__ __launch_bounds__(256) void scan_phase2(const float* __restrict__ cvp,
                                                   const float* __restrict__ chp,
                                                   float* __restrict__ gp,
                                                   float* __restrict__ rp) {
  int i = blockIdx.x * 256 + threadIdx.x;  // 49152 = 2*1536*16
  int b = i / (D_INNER * 16);
  int rem = i % (D_INNER * 16);
  float v0 = 0.f, h0 = 0.f;
#pragma unroll
  for (int c = 0; c < CCH; c++) {
    size_t o = ((size_t)(b * CCH + c)) * (D_INNER * 16) + rem;
    float cv = cvp[o], ch = chp[o], gg = gp[o], rr = rp[o];
    gp[o] = v0;  // v0 for chunk c
    rp[o] = h0;  // h0 for chunk c
    float v0n = fmaf(BETA_CL, v0, cv);
    float h0n = fmaf(gg, v0, fmaf(rr, h0, ch));
    v0 = v0n;
    h0 = h0n;
  }
}

// phase 3: per chunk from composed state, emit y
__global__ __launch_bounds__(64) void scan_phase3(const float* __restrict__ ubuf,
                                                  const float* __restrict__ dtbuf,
                                                  const float* __restrict__ kqbuf,
                                                  const float* __restrict__ gp,
                                                  const float* __restrict__ rp,
                                                  float* __restrict__ ybuf) {
  __shared__ float u_s[2][32][16];
  __shared__ float dt_s[2][32][16];
  __shared__ __align__(16) float kq_s[2][32][32];
  const int t = threadIdx.x;
  const int nq = t & 3, dloc = t >> 2;
  const int b = blockIdx.x / (96 * CCH);
  const int rem = blockIdx.x % (96 * CCH);
  const int d0 = (rem / CCH) * 16;
  const int c = rem % CCH;
  const int tbase = c * CLEN;
  const size_t ub = (size_t)b * LSEQ * D_INNER + d0;
  const float* kqb = kqbuf + (size_t)b * LSEQ * 32;
  float* y_p = ybuf + (size_t)b * LSEQ * D_INNER + d0 + dloc;
  const int scol = t & 15, srow0 = t >> 4;
  const int krow0 = t >> 3, kcol = (t & 7) * 4;
  float pu[8], pd[8];
  f32x4 pk[4];
  auto prefetch = [&](int t0) {
#pragma unroll
    for (int i = 0; i < 8; i++) {
      size_t off = ub + (size_t)(t0 + srow0 + 4 * i) * D_INNER + scol;
      pu[i] = ubuf[off];
      pd[i] = dtbuf[off];
    }
#pragma unroll
    for (int i = 0; i < 4; i++)
      pk[i] = *(const f32x4*)(kqb + (size_t)(t0 + krow0 + 8 * i) * 32 + kcol);
  };
  auto writelds = [&](int bi) {
#pragma unroll
    for (int i = 0; i < 8; i++) {
      u_s[bi][srow0 + 4 * i][scol] = pu[i];
      dt_s[bi][srow0 + 4 * i][scol] = pd[i];
    }
#pragma unroll
    for (int i = 0; i < 4; i++)
      *(f32x4*)&kq_s[bi][krow0 + 8 * i][kcol] = pk[i];
  };
  size_t so = (((size_t)b * CCH + c) * D_INNER + d0 + dloc) * 16 + nq * 4;
  f32x4 v = *(const f32x4*)(gp + so);
  f32x4 h = *(const f32x4*)(rp + so);
  prefetch(tbase);
  writelds(0);
  int buf = 0;
  for (int t0 = 0; t0 < CLEN; t0 += 32) {
    const bool more = (t0 + 32 < CLEN);
    if (more) prefetch(tbase + t0 + 32);
#pragma unroll 4
    for (int s = 0; s < 32; s++) {
      float u = u_s[buf][s][dloc];
      float dtf = dt_s[buf][s][dloc];
      f32x4 kv = *(const f32x4*)&kq_s[buf][s][nq * 4];
      f32x4 qv = *(const f32x4*)&kq_s[buf][s][16 + nq * 4];
      float yp = 0.0f;
#pragma unroll
      for (int j = 0; j < 4; j++) {
        float kj = kv[j];
        v[j] = fmaf(0.9f, v[j], u * kj);
        float dA = fmaf(-dtf * kj, kj, 1.0f);
        h[j] = fmaf(dA, h[j], v[j]);
        yp = fmaf(h[j], qv[j], yp);
      }
      yp += __shfl_xor(yp, 1);
      yp += __shfl_xor(yp, 2);
      if (nq == 0) y_p[(size_t)(tbase + t0 + s) * D_INNER] = yp;
    }
    if (more) writelds(buf ^ 1);
    buf ^= 1;
  }
}

// ---- gate: yg = (y_scan + D*xconv) * silu(z) ----
__global__ __launch_bounds__(256) void gate_kernel(const float* __restrict__ ybuf,
                                                   const float* __restrict__ xconv,
                                                   const float* __restrict__ xz,
                                                   const float* __restrict__ Dp,
                                                   float* __restrict__ yg) {
  int idx = blockIdx.x * 256 + threadIdx.x;
  if (idx >= NROWS * D_INNER) return;
  int c = idx % D_INNER;
  int row = idx / D_INNER;
  float z = xz[(size_t)row * 3072 + 1536 + c];
  float sz = z / (1.0f + expf(-z));
  yg[idx] = (ybuf[idx] + Dp[c] * xconv[idx]) * sz;
}

extern "C" void kernel_launch(void* const* d_in, const int* in_sizes, int n_in,
                              void* d_out, int out_size, void* d_ws, size_t ws_size,
                              hipStream_t stream) {
  const float* hidden = (const float*)d_in[0];
  const float* w_in   = (const float*)d_in[1];
  const float* conv_w = (const float*)d_in[2];
  const float* conv_b = (const float*)d_in[3];
  const float* w_x    = (const float*)d_in[4];
  const float* w_dt   = (const float*)d_in[5];
  const float* b_dt   = (const float*)d_in[6];
  const float* w_out  = (const float*)d_in[7];
  const float* Dp     = (const float*)d_in[8];

  float* ws    = (float*)d_ws;
  float* xz    = ws;                                  // 2048*3072
  float* xconv = xz + (size_t)NROWS * 3072;           // 2048*1536
  float* xdbl  = xconv + (size_t)NROWS * D_INNER;     // 2048*80
  float* dtbuf = xdbl + (size_t)NROWS * 80;           // 2048*1536
  float* ubuf  = dtbuf + (size_t)NROWS * D_INNER;     // 2048*1536
  float* kqbuf = ubuf + (size_t)NROWS * D_INNER;      // 2048*32
  float* ybuf  = kqbuf + (size_t)NROWS * 32;          // 2048*1536
  const size_t PL = (size_t)NB * CCH * D_INNER * 16;  // 393216 per plane
  float* cvp   = ybuf + (size_t)NROWS * D_INNER;      // 4 planes, 6.3 MB total
  float* chp   = cvp + PL;
  float* gp    = chp + PL;
  float* rp    = gp + PL;
  float* yg    = ubuf;                                // reuse after scan

  dim3 blk(256);
  // 1. in_proj: xz = hidden @ W_in^T  (2048 x 3072, K=768)
  gemm_bt<<<dim3(48, 32), blk, 0, stream>>>(hidden, w_in, xz, 2048, 3072, 768, 768, 768, 3072);
  // 2. causal conv + SiLU
  conv_silu_kernel<<<dim3(12288), blk, 0, stream>>>(xz, conv_w, conv_b, xconv);
  // 3. x_proj: xdbl = xconv @ W_x^T  (2048 x 80, K=1536)
  gemm_bt<<<dim3(2, 32), blk, 0, stream>>>(xconv, w_x, xdbl, 2048, 80, 1536, 1536, 1536, 80);
  // 4. dt_head: dt_raw = dt_low @ W_dt^T  (2048 x 1536, K=48, lda=80)
  gemm_bt<<<dim3(24, 32), blk, 0, stream>>>(xdbl, w_dt, dtbuf, 2048, 1536, 48, 80, 48, 1536);
  // 5. precompute dt-final, gamma, u', k, q
  precompute_kernel<<<dim3(NROWS), blk, 0, stream>>>(xdbl, dtbuf, xconv, b_dt, ubuf, kqbuf);
  // 6. segmented scan: 3 phases (1536 blocks -> 6 waves/CU in ph1/ph3)
  scan_phase1<<<dim3(NB * 96 * CCH), dim3(64), 0, stream>>>(ubuf, dtbuf, kqbuf, cvp, chp, gp, rp);
  scan_phase2<<<dim3(192), blk, 0, stream>>>(cvp, chp, gp, rp);
  scan_phase3<<<dim3(NB * 96 * CCH), dim3(64), 0, stream>>>(ubuf, dtbuf, kqbuf, gp, rp, ybuf);
  // 7. gate
  gate_kernel<<<dim3(12288), blk, 0, stream>>>(ybuf, xconv, xz, Dp, yg);
  // 8. out_proj -> FP32 d_out  (2048 x 768, K=1536)
  gemm_bt<<<dim3(12, 32), blk, 0, stream>>>(yg, w_out, (float*)d_out, 2048, 768, 1536,
                                            1536, 1536, 768);
}

// Round 9
// 242.131 us; speedup vs baseline: 3.0145x; 1.2215x over previous
//
#include <hip/hip_runtime.h>

#define D_MODEL 768
#define D_STATE 16
#define D_INNER 1536
#define DT_RANK 48
#define NB 2
#define LSEQ 1024
#define NROWS (NB * LSEQ)
#define CCH 8                  // chunks over L
#define CLEN (LSEQ / CCH)      // 128 steps per chunk
#define BETA_CL 1.3900845e-06f // 0.9^128

typedef __attribute__((ext_vector_type(4))) float f32x4;
typedef __attribute__((ext_vector_type(8))) short s16x8;
typedef __attribute__((ext_vector_type(8))) unsigned short u16x8;

__device__ __forceinline__ unsigned short f2bu(float f) {
  unsigned int x = __builtin_bit_cast(unsigned int, f);
  x += 0x7fffu + ((x >> 16) & 1u);
  return (unsigned short)(x >> 16);
}

// ---- C = A * B^T GEMM, bf16 MFMA, fp32 accum ----
// Register-prefetch + double-buffered LDS; optional split-K with atomic epilogue.
template <bool ATOMIC>
__global__ __launch_bounds__(256) void gemm_bt(const float* __restrict__ A,
                                               const float* __restrict__ B,
                                               float* __restrict__ C, int M, int N, int K,
                                               int lda, int ldb, int ldc, int kseg_len) {
  __shared__ __align__(16) unsigned short As[2][64][40];
  __shared__ __align__(16) unsigned short Bs[2][64][40];
  const int m0 = blockIdx.y * 64, n0 = blockIdx.x * 64;
  const int kbeg = blockIdx.z * kseg_len;
  const int kend = (kbeg + kseg_len < K) ? (kbeg + kseg_len) : K;
  const int t = threadIdx.x;
  const int wave = t >> 6, lane = t & 63;
  const int wm = wave >> 1, wn = wave & 1;
  const int quad = lane >> 4, l16 = lane & 15;
  const int srow = t >> 2;
  const int kseg = (t & 3) * 8;
  const float* Ap = A + (size_t)(m0 + srow) * lda;
  const float* Bp = B + (size_t)(n0 + srow) * ldb;
  const bool va = (m0 + srow) < M, vb = (n0 + srow) < N;

  f32x4 ra0, ra1, rb0, rb1;
  auto pref = [&](int k0) {
    const int kk = k0 + kseg;
    const int krem = kend - kk;
    if (va && krem >= 8) {
      ra0 = *(const f32x4*)(Ap + kk);
      ra1 = *(const f32x4*)(Ap + kk + 4);
    } else {
#pragma unroll
      for (int j = 0; j < 4; j++) {
        ra0[j] = (va && j < krem) ? Ap[kk + j] : 0.0f;
        ra1[j] = (va && j + 4 < krem) ? Ap[kk + j + 4] : 0.0f;
      }
    }
    if (vb && krem >= 8) {
      rb0 = *(const f32x4*)(Bp + kk);
      rb1 = *(const f32x4*)(Bp + kk + 4);
    } else {
#pragma unroll
      for (int j = 0; j < 4; j++) {
        rb0[j] = (vb && j < krem) ? Bp[kk + j] : 0.0f;
        rb1[j] = (vb && j + 4 < krem) ? Bp[kk + j + 4] : 0.0f;
      }
    }
  };
  auto tolds = [&](int bi) {
    u16x8 oa, ob;
#pragma unroll
    for (int j = 0; j < 4; j++) {
      oa[j] = f2bu(ra0[j]); oa[4 + j] = f2bu(ra1[j]);
      ob[j] = f2bu(rb0[j]); ob[4 + j] = f2bu(rb1[j]);
    }
    *(u16x8*)&As[bi][srow][kseg] = oa;
    *(u16x8*)&Bs[bi][srow][kseg] = ob;
  };

  f32x4 acc[2][2] = {};
  pref(kbeg);
  tolds(0);
  __syncthreads();
  int buf = 0;
  for (int k0 = kbeg; k0 < kend; k0 += 32) {
    const bool more = (k0 + 32 < kend);
    if (more) pref(k0 + 32);  // loads in flight during compute
    s16x8 a0 = *(const s16x8*)&As[buf][wm * 32 + l16][quad * 8];
    s16x8 a1 = *(const s16x8*)&As[buf][wm * 32 + 16 + l16][quad * 8];
    s16x8 b0 = *(const s16x8*)&Bs[buf][wn * 32 + l16][quad * 8];
    s16x8 b1 = *(const s16x8*)&Bs[buf][wn * 32 + 16 + l16][quad * 8];
    acc[0][0] = __builtin_amdgcn_mfma_f32_16x16x32_bf16(a0, b0, acc[0][0], 0, 0, 0);
    acc[0][1] = __builtin_amdgcn_mfma_f32_16x16x32_bf16(a0, b1, acc[0][1], 0, 0, 0);
    acc[1][0] = __builtin_amdgcn_mfma_f32_16x16x32_bf16(a1, b0, acc[1][0], 0, 0, 0);
    acc[1][1] = __builtin_amdgcn_mfma_f32_16x16x32_bf16(a1, b1, acc[1][1], 0, 0, 0);
    if (more) tolds(buf ^ 1);  // write other buffer after reads of this one
    __syncthreads();
    buf ^= 1;
  }
#pragma unroll
  for (int mi = 0; mi < 2; mi++)
#pragma unroll
    for (int ni = 0; ni < 2; ni++)
#pragma unroll
      for (int r = 0; r < 4; r++) {
        int row = m0 + wm * 32 + mi * 16 + quad * 4 + r;
        int col = n0 + wn * 32 + ni * 16 + l16;
        if (row < M && col < N) {
          if constexpr (ATOMIC)
            atomicAdd(&C[(size_t)row * ldc + col], acc[mi][ni][r]);
          else
            C[(size_t)row * ldc + col] = acc[mi][ni][r];
        }
      }
}

// ---- causal depthwise conv (width 4) + SiLU ----
__global__ __launch_bounds__(256) void conv_silu_kernel(const float* __restrict__ xz,
                                                        const float* __restrict__ cw,
                                                        const float* __restrict__ cb,
                                                        float* __restrict__ xc) {
  int idx = blockIdx.x * 256 + threadIdx.x;
  if (idx >= NROWS * D_INNER) return;
  int c = idx % D_INNER;
  int row = idx / D_INNER;
  int l = row & (LSEQ - 1);
  float acc = cb[c];
#pragma unroll
  for (int j = 0; j < 4; j++) {
    int dl = l - 3 + j;
    if (dl >= 0) acc += xz[(size_t)(row - 3 + j) * 3072 + c] * cw[c * 4 + j];
  }
  float sg = 1.0f / (1.0f + expf(-acc));
  xc[idx] = acc * sg;
}

// ---- per (b,l): dt transform, closed-form rank-1 NS gamma, u' = gamma*dt*x ----
__global__ __launch_bounds__(256) void precompute_kernel(const float* __restrict__ xdbl,
                                                         float* __restrict__ dtbuf,
                                                         const float* __restrict__ xconv,
                                                         const float* __restrict__ dtb,
                                                         float* __restrict__ ubuf,
                                                         float* __restrict__ kqbuf) {
  int row = blockIdx.x;
  int t = threadIdx.x;
  const float* xr = xdbl + (size_t)row * 80;
  float nk = 0.0f;
#pragma unroll
  for (int n = 0; n < 16; n++) { float kv = xr[48 + n]; nk += kv * kv; }
  float dtf[6], u0[6];
  float nupart = 0.0f;
#pragma unroll
  for (int i = 0; i < 6; i++) {
    int d = i * 256 + t;
    float draw = dtbuf[(size_t)row * D_INNER + d] + dtb[d];
    float sg = 1.0f / (1.0f + expf(-draw));
    float dv = sg / (1.0f + sg * nk);
    dtf[i] = dv;
    float u = dv * xconv[(size_t)row * D_INNER + d];
    u0[i] = u;
    nupart += u * u;
  }
  __shared__ float red[4];
  float v = nupart;
#pragma unroll
  for (int off = 32; off > 0; off >>= 1) v += __shfl_xor(v, off);
  if ((t & 63) == 0) red[t >> 6] = v;
  __syncthreads();
  float nu = red[0] + red[1] + red[2] + red[3];
  float p = nu * nk;
  float s = sqrtf(p) + 1e-7f;
  float tt = p / (s * s);
  float gamma = (3.4445f + tt * (-4.7750f + 2.0315f * tt)) / s;
#pragma unroll
  for (int i = 0; i < 6; i++) {
    int d = i * 256 + t;
    dtbuf[(size_t)row * D_INNER + d] = dtf[i];
    ubuf[(size_t)row * D_INNER + d] = gamma * u0[i];
  }
  if (t < 16) {
    kqbuf[(size_t)row * 32 + t] = xr[48 + t];       // k
    kqbuf[(size_t)row * 32 + 16 + t] = xr[64 + t];  // q
  }
}

// ================= segmented scan =================
// phase 1: per chunk from zero state -> cv, ch, g, r
__global__ __launch_bounds__(64) void scan_phase1(const float* __restrict__ ubuf,
                                                  const float* __restrict__ dtbuf,
                                                  const float* __restrict__ kqbuf,
                                                  float* __restrict__ cvp,
                                                  float* __restrict__ chp,
                                                  float* __restrict__ gp,
                                                  float* __restrict__ rp) {
  __shared__ float u_s[2][32][16];
  __shared__ float dt_s[2][32][16];
  __shared__ __align__(16) float kq_s[2][32][32];
  const int t = threadIdx.x;
  const int nq = t & 3, dloc = t >> 2;
  const int b = blockIdx.x / (96 * CCH);
  const int rem = blockIdx.x % (96 * CCH);
  const int d0 = (rem / CCH) * 16;
  const int c = rem % CCH;
  const int tbase = c * CLEN;
  const size_t ub = (size_t)b * LSEQ * D_INNER + d0;
  const float* kqb = kqbuf + (size_t)b * LSEQ * 32;
  const int scol = t & 15, srow0 = t >> 4;
  const int krow0 = t >> 3, kcol = (t & 7) * 4;
  float pu[8], pd[8];
  f32x4 pk[4];
  auto prefetch = [&](int t0) {
#pragma unroll
    for (int i = 0; i < 8; i++) {
      size_t off = ub + (size_t)(t0 + srow0 + 4 * i) * D_INNER + scol;
      pu[i] = ubuf[off];
      pd[i] = dtbuf[off];
    }
#pragma unroll
    for (int i = 0; i < 4; i++)
      pk[i] = *(const f32x4*)(kqb + (size_t)(t0 + krow0 + 8 * i) * 32 + kcol);
  };
  auto writelds = [&](int bi) {
#pragma unroll
    for (int i = 0; i < 8; i++) {
      u_s[bi][srow0 + 4 * i][scol] = pu[i];
      dt_s[bi][srow0 + 4 * i][scol] = pd[i];
    }
#pragma unroll
    for (int i = 0; i < 4; i++)
      *(f32x4*)&kq_s[bi][krow0 + 8 * i][kcol] = pk[i];
  };
  f32x4 v = {0.f, 0.f, 0.f, 0.f}, h = {0.f, 0.f, 0.f, 0.f};
  f32x4 g = {0.f, 0.f, 0.f, 0.f}, r = {1.f, 1.f, 1.f, 1.f};
  float bt = 0.9f;
  prefetch(tbase);
  writelds(0);
  int buf = 0;
  for (int t0 = 0; t0 < CLEN; t0 += 32) {
    const bool more = (t0 + 32 < CLEN);
    if (more) prefetch(tbase + t0 + 32);
#pragma unroll 4
    for (int s = 0; s < 32; s++) {
      float u = u_s[buf][s][dloc];
      float dtf = dt_s[buf][s][dloc];
      f32x4 kv = *(const f32x4*)&kq_s[buf][s][nq * 4];
#pragma unroll
      for (int j = 0; j < 4; j++) {
        float kj = kv[j];
        v[j] = fmaf(0.9f, v[j], u * kj);
        float a = fmaf(-dtf * kj, kj, 1.0f);
        h[j] = fmaf(a, h[j], v[j]);
        r[j] *= a;
        g[j] = fmaf(a, g[j], bt);
      }
      bt *= 0.9f;
    }
    if (more) writelds(buf ^ 1);
    buf ^= 1;
  }
  size_t o = (((size_t)b * CCH + c) * D_INNER + d0 + dloc) * 16 + nq * 4;
  *(f32x4*)(cvp + o) = v;
  *(f32x4*)(chp + o) = h;
  *(f32x4*)(gp + o) = g;
  *(f32x4*)(rp + o) = r;
}

// phase 2: compose chunk transfers -> per-chunk initial state, in-place over g/r
__global__ __launch_bounds__(256) void scan_phase2(const float* __restrict__ cvp,
                                                   const float* __restrict__ chp,
                                                   float* __restrict__ gp,
                                                   float* __restrict__ rp) {
  int i = blockIdx.x * 256 + threadIdx.x;  // 49152 = 2*1536*16
  int b = i / (D_INNER * 16);
  int rem = i % (D_INNER * 16);
  float v0 = 0.f, h0 = 0.f;
#pragma unroll
  for (int c = 0; c < CCH; c++) {
    size_t o = ((size_t)(b * CCH + c)) * (D_INNER * 16) + rem;
    float cv = cvp[o], ch = chp[o], gg = gp[o], rr = rp[o];
    gp[o] = v0;
    rp[o] = h0;
    float v0n = fmaf(BETA_CL, v0, cv);
    float h0n = fmaf(gg, v0, fmaf(rr, h0, ch));
    v0 = v0n;
    h0 = h0n;
  }
}

// phase 3: per chunk from composed state, emit y
__global__ __launch_bounds__(64) void scan_phase3(const float* __restrict__ ubuf,
                                                  const float* __restrict__ dtbuf,
                                                  const float* __restrict__ kqbuf,
                                                  const float* __restrict__ gp,
                                                  const float* __restrict__ rp,
                                                  float* __restrict__ ybuf) {
  __shared__ float u_s[2][32][16];
  __shared__ float dt_s[2][32][16];
  __shared__ __align__(16) float kq_s[2][32][32];
  const int t = threadIdx.x;
  const int nq = t & 3, dloc = t >> 2;
  const int b = blockIdx.x / (96 * CCH);
  const int rem = blockIdx.x % (96 * CCH);
  const int d0 = (rem / CCH) * 16;
  const int c = rem % CCH;
  const int tbase = c * CLEN;
  const size_t ub = (size_t)b * LSEQ * D_INNER + d0;
  const float* kqb = kqbuf + (size_t)b * LSEQ * 32;
  float* y_p = ybuf + (size_t)b * LSEQ * D_INNER + d0 + dloc;
  const int scol = t & 15, srow0 = t >> 4;
  const int krow0 = t >> 3, kcol = (t & 7) * 4;
  float pu[8], pd[8];
  f32x4 pk[4];
  auto prefetch = [&](int t0) {
#pragma unroll
    for (int i = 0; i < 8; i++) {
      size_t off = ub + (size_t)(t0 + srow0 + 4 * i) * D_INNER + scol;
      pu[i] = ubuf[off];
      pd[i] = dtbuf[off];
    }
#pragma unroll
    for (int i = 0; i < 4; i++)
      pk[i] = *(const f32x4*)(kqb + (size_t)(t0 + krow0 + 8 * i) * 32 + kcol);
  };
  auto writelds = [&](int bi) {
#pragma unroll
    for (int i = 0; i < 8; i++) {
      u_s[bi][srow0 + 4 * i][scol] = pu[i];
      dt_s[bi][srow0 + 4 * i][scol] = pd[i];
    }
#pragma unroll
    for (int i = 0; i < 4; i++)
      *(f32x4*)&kq_s[bi][krow0 + 8 * i][kcol] = pk[i];
  };
  size_t so = (((size_t)b * CCH + c) * D_INNER + d0 + dloc) * 16 + nq * 4;
  f32x4 v = *(const f32x4*)(gp + so);
  f32x4 h = *(const f32x4*)(rp + so);
  prefetch(tbase);
  writelds(0);
  int buf = 0;
  for (int t0 = 0; t0 < CLEN; t0 += 32) {
    const bool more = (t0 + 32 < CLEN);
    if (more) prefetch(tbase + t0 + 32);
#pragma unroll 4
    for (int s = 0; s < 32; s++) {
      float u = u_s[buf][s][dloc];
      float dtf = dt_s[buf][s][dloc];
      f32x4 kv = *(const f32x4*)&kq_s[buf][s][nq * 4];
      f32x4 qv = *(const f32x4*)&kq_s[buf][s][16 + nq * 4];
      float yp = 0.0f;
#pragma unroll
      for (int j = 0; j < 4; j++) {
        float kj = kv[j];
        v[j] = fmaf(0.9f, v[j], u * kj);
        float dA = fmaf(-dtf * kj, kj, 1.0f);
        h[j] = fmaf(dA, h[j], v[j]);
        yp = fmaf(h[j], qv[j], yp);
      }
      yp += __shfl_xor(yp, 1);
      yp += __shfl_xor(yp, 2);
      if (nq == 0) y_p[(size_t)(tbase + t0 + s) * D_INNER] = yp;
    }
    if (more) writelds(buf ^ 1);
    buf ^= 1;
  }
}

// ---- gate: yg = (y_scan + D*xconv) * silu(z) ----
__global__ __launch_bounds__(256) void gate_kernel(const float* __restrict__ ybuf,
                                                   const float* __restrict__ xconv,
                                                   const float* __restrict__ xz,
                                                   const float* __restrict__ Dp,
                                                   float* __restrict__ yg) {
  int idx = blockIdx.x * 256 + threadIdx.x;
  if (idx >= NROWS * D_INNER) return;
  int c = idx % D_INNER;
  int row = idx / D_INNER;
  float z = xz[(size_t)row * 3072 + 1536 + c];
  float sz = z / (1.0f + expf(-z));
  yg[idx] = (ybuf[idx] + Dp[c] * xconv[idx]) * sz;
}

extern "C" void kernel_launch(void* const* d_in, const int* in_sizes, int n_in,
                              void* d_out, int out_size, void* d_ws, size_t ws_size,
                              hipStream_t stream) {
  const float* hidden = (const float*)d_in[0];
  const float* w_in   = (const float*)d_in[1];
  const float* conv_w = (const float*)d_in[2];
  const float* conv_b = (const float*)d_in[3];
  const float* w_x    = (const float*)d_in[4];
  const float* w_dt   = (const float*)d_in[5];
  const float* b_dt   = (const float*)d_in[6];
  const float* w_out  = (const float*)d_in[7];
  const float* Dp     = (const float*)d_in[8];

  float* ws    = (float*)d_ws;
  float* xz    = ws;                                  // 2048*3072
  float* xconv = xz + (size_t)NROWS * 3072;           // 2048*1536
  float* xdbl  = xconv + (size_t)NROWS * D_INNER;     // 2048*80
  float* dtbuf = xdbl + (size_t)NROWS * 80;           // 2048*1536
  float* ubuf  = dtbuf + (size_t)NROWS * D_INNER;     // 2048*1536
  float* kqbuf = ubuf + (size_t)NROWS * D_INNER;      // 2048*32
  float* ybuf  = kqbuf + (size_t)NROWS * 32;          // 2048*1536
  const size_t PL = (size_t)NB * CCH * D_INNER * 16;  // 393216 per plane
  float* cvp   = ybuf + (size_t)NROWS * D_INNER;      // 4 planes
  float* chp   = cvp + PL;
  float* gp    = chp + PL;
  float* rp    = gp + PL;
  float* yg    = ubuf;                                // reuse after scan

  dim3 blk(256);
  // zero-init split-K atomic targets (graph-capture-safe)
  hipMemsetAsync(xdbl, 0, (size_t)NROWS * 80 * 4, stream);
  hipMemsetAsync(d_out, 0, (size_t)NROWS * 768 * 4, stream);

  // 1. in_proj: xz = hidden @ W_in^T  (2048 x 3072, K=768), 1536 blocks
  gemm_bt<false><<<dim3(48, 32, 1), blk, 0, stream>>>(hidden, w_in, xz, 2048, 3072, 768,
                                                      768, 768, 3072, 768);
  // 2. causal conv + SiLU
  conv_silu_kernel<<<dim3(12288), blk, 0, stream>>>(xz, conv_w, conv_b, xconv);
  // 3. x_proj: split-K=8 (Kseg 192), 512 blocks, atomic epilogue
  gemm_bt<true><<<dim3(2, 32, 8), blk, 0, stream>>>(xconv, w_x, xdbl, 2048, 80, 1536,
                                                    1536, 1536, 80, 192);
  // 4. dt_head: K=48, 768 blocks
  gemm_bt<false><<<dim3(24, 32, 1), blk, 0, stream>>>(xdbl, w_dt, dtbuf, 2048, 1536, 48,
                                                      80, 48, 1536, 48);
  // 5. precompute dt-final, gamma, u', k, q
  precompute_kernel<<<dim3(NROWS), blk, 0, stream>>>(xdbl, dtbuf, xconv, b_dt, ubuf, kqbuf);
  // 6. segmented scan: 3 phases
  scan_phase1<<<dim3(NB * 96 * CCH), dim3(64), 0, stream>>>(ubuf, dtbuf, kqbuf, cvp, chp, gp, rp);
  scan_phase2<<<dim3(192), blk, 0, stream>>>(cvp, chp, gp, rp);
  scan_phase3<<<dim3(NB * 96 * CCH), dim3(64), 0, stream>>>(ubuf, dtbuf, kqbuf, gp, rp, ybuf);
  // 7. gate
  gate_kernel<<<dim3(12288), blk, 0, stream>>>(ybuf, xconv, xz, Dp, yg);
  // 8. out_proj: split-K=2 (Kseg 768), 768 blocks, atomic epilogue -> FP32 d_out
  gemm_bt<true><<<dim3(12, 32, 2), blk, 0, stream>>>(yg, w_out, (float*)d_out, 2048, 768, 1536,
                                                     1536, 1536, 768, 768);
}

// Round 10
// 239.794 us; speedup vs baseline: 3.0438x; 1.0097x over previous
//
#include <hip/hip_runtime.h>

#define D_MODEL 768
#define D_STATE 16
#define D_INNER 1536
#define DT_RANK 48
#define NB 2
#define LSEQ 1024
#define NROWS (NB * LSEQ)
#define CCH 8                  // chunks over L
#define CLEN (LSEQ / CCH)      // 128 steps per chunk
#define BETA_CL 1.3900845e-06f // 0.9^128

typedef __attribute__((ext_vector_type(4))) float f32x4;
typedef __attribute__((ext_vector_type(8))) short s16x8;
typedef __attribute__((ext_vector_type(8))) unsigned short u16x8;

__device__ __forceinline__ unsigned short f2bu(float f) {
  unsigned int x = __builtin_bit_cast(unsigned int, f);
  x += 0x7fffu + ((x >> 16) & 1u);
  return (unsigned short)(x >> 16);
}

// ---- one-shot fp32 -> bf16 conversion of the 5 static GEMM operands ----
// segments (in 8-elem groups): hidden 196608 | w_in 294912 | w_x 15360 | w_dt 9216 | w_out 147456
#define CVT_TOTAL 663552
__global__ __launch_bounds__(256) void cvt5_kernel(const float* __restrict__ s0,
                                                   const float* __restrict__ s1,
                                                   const float* __restrict__ s2,
                                                   const float* __restrict__ s3,
                                                   const float* __restrict__ s4,
                                                   unsigned short* __restrict__ d0,
                                                   unsigned short* __restrict__ d1,
                                                   unsigned short* __restrict__ d2,
                                                   unsigned short* __restrict__ d3,
                                                   unsigned short* __restrict__ d4) {
  int g = blockIdx.x * 256 + threadIdx.x;
  if (g >= CVT_TOTAL) return;
  const float* s;
  unsigned short* d;
  int base;
  if (g < 196608)      { s = s0; d = d0; base = 0; }
  else if (g < 491520) { s = s1; d = d1; base = 196608; }
  else if (g < 506880) { s = s2; d = d2; base = 491520; }
  else if (g < 516096) { s = s3; d = d3; base = 506880; }
  else                 { s = s4; d = d4; base = 516096; }
  int i = (g - base) * 8;
  f32x4 a = *(const f32x4*)(s + i);
  f32x4 b = *(const f32x4*)(s + i + 4);
  u16x8 o;
#pragma unroll
  for (int j = 0; j < 4; j++) { o[j] = f2bu(a[j]); o[4 + j] = f2bu(b[j]); }
  *(u16x8*)(d + i) = o;
}

// ---- C = A * B^T GEMM, bf16 MFMA, fp32 accum ----
// B always pre-converted bf16. A bf16 (AF32=false) or fp32-with-cvt (AF32=true).
// Register-prefetch + double-buffered LDS; optional split-K atomic epilogue.
template <bool AF32, bool ATOMIC>
__global__ __launch_bounds__(256) void gemm_bt(const void* __restrict__ Av,
                                               const unsigned short* __restrict__ B,
                                               float* __restrict__ C, int M, int N, int K,
                                               int lda, int ldb, int ldc, int kseg_len) {
  __shared__ __align__(16) unsigned short As[2][64][40];
  __shared__ __align__(16) unsigned short Bs[2][64][40];
  const int m0 = blockIdx.y * 64, n0 = blockIdx.x * 64;
  const int kbeg = blockIdx.z * kseg_len;
  const int kend = (kbeg + kseg_len < K) ? (kbeg + kseg_len) : K;
  const int t = threadIdx.x;
  const int wave = t >> 6, lane = t & 63;
  const int wm = wave >> 1, wn = wave & 1;
  const int quad = lane >> 4, l16 = lane & 15;
  const int srow = t >> 2;
  const int kseg = (t & 3) * 8;
  const bool va = (m0 + srow) < M, vb = (n0 + srow) < N;
  const float* Af = (const float*)Av;
  const unsigned short* Ab = (const unsigned short*)Av;
  const unsigned short* Bp = B + (size_t)(n0 + srow) * ldb;

  f32x4 ra0, ra1;  // AF32 path regs
  u16x8 rab;       // bf16-A path regs
  u16x8 rbb;
  auto pref = [&](int k0) {
    const int kk = k0 + kseg;
    const int krem = kend - kk;
    if constexpr (AF32) {
      const float* Ap = Af + (size_t)(m0 + srow) * lda + kk;
      if (va && krem >= 8) {
        ra0 = *(const f32x4*)Ap;
        ra1 = *(const f32x4*)(Ap + 4);
      } else {
#pragma unroll
        for (int j = 0; j < 4; j++) {
          ra0[j] = (va && j < krem) ? Ap[j] : 0.0f;
          ra1[j] = (va && j + 4 < krem) ? Ap[j + 4] : 0.0f;
        }
      }
    } else {
      const unsigned short* Ap = Ab + (size_t)(m0 + srow) * lda + kk;
      if (va && krem >= 8) {
        rab = *(const u16x8*)Ap;
      } else {
#pragma unroll
        for (int j = 0; j < 8; j++) rab[j] = (va && j < krem) ? Ap[j] : (unsigned short)0;
      }
    }
    if (vb && krem >= 8) {
      rbb = *(const u16x8*)(Bp + kk);
    } else {
#pragma unroll
      for (int j = 0; j < 8; j++) rbb[j] = (vb && j < krem) ? Bp[kk + j] : (unsigned short)0;
    }
  };
  auto tolds = [&](int bi) {
    if constexpr (AF32) {
      u16x8 oa;
#pragma unroll
      for (int j = 0; j < 4; j++) { oa[j] = f2bu(ra0[j]); oa[4 + j] = f2bu(ra1[j]); }
      *(u16x8*)&As[bi][srow][kseg] = oa;
    } else {
      *(u16x8*)&As[bi][srow][kseg] = rab;
    }
    *(u16x8*)&Bs[bi][srow][kseg] = rbb;
  };

  f32x4 acc[2][2] = {};
  pref(kbeg);
  tolds(0);
  __syncthreads();
  int buf = 0;
  for (int k0 = kbeg; k0 < kend; k0 += 32) {
    const bool more = (k0 + 32 < kend);
    if (more) pref(k0 + 32);  // loads in flight during compute
    s16x8 a0 = *(const s16x8*)&As[buf][wm * 32 + l16][quad * 8];
    s16x8 a1 = *(const s16x8*)&As[buf][wm * 32 + 16 + l16][quad * 8];
    s16x8 b0 = *(const s16x8*)&Bs[buf][wn * 32 + l16][quad * 8];
    s16x8 b1 = *(const s16x8*)&Bs[buf][wn * 32 + 16 + l16][quad * 8];
    acc[0][0] = __builtin_amdgcn_mfma_f32_16x16x32_bf16(a0, b0, acc[0][0], 0, 0, 0);
    acc[0][1] = __builtin_amdgcn_mfma_f32_16x16x32_bf16(a0, b1, acc[0][1], 0, 0, 0);
    acc[1][0] = __builtin_amdgcn_mfma_f32_16x16x32_bf16(a1, b0, acc[1][0], 0, 0, 0);
    acc[1][1] = __builtin_amdgcn_mfma_f32_16x16x32_bf16(a1, b1, acc[1][1], 0, 0, 0);
    if (more) tolds(buf ^ 1);
    __syncthreads();
    buf ^= 1;
  }
#pragma unroll
  for (int mi = 0; mi < 2; mi++)
#pragma unroll
    for (int ni = 0; ni < 2; ni++)
#pragma unroll
      for (int r = 0; r < 4; r++) {
        int row = m0 + wm * 32 + mi * 16 + quad * 4 + r;
        int col = n0 + wn * 32 + ni * 16 + l16;
        if (row < M && col < N) {
          if constexpr (ATOMIC)
            atomicAdd(&C[(size_t)row * ldc + col], acc[mi][ni][r]);
          else
            C[(size_t)row * ldc + col] = acc[mi][ni][r];
        }
      }
}

// ---- causal depthwise conv (width 4) + SiLU; emits fp32 + bf16 copies ----
__global__ __launch_bounds__(256) void conv_silu_kernel(const float* __restrict__ xz,
                                                        const float* __restrict__ cw,
                                                        const float* __restrict__ cb,
                                                        float* __restrict__ xc,
                                                        unsigned short* __restrict__ xcb) {
  int idx = blockIdx.x * 256 + threadIdx.x;
  if (idx >= NROWS * D_INNER) return;
  int c = idx % D_INNER;
  int row = idx / D_INNER;
  int l = row & (LSEQ - 1);
  float acc = cb[c];
#pragma unroll
  for (int j = 0; j < 4; j++) {
    int dl = l - 3 + j;
    if (dl >= 0) acc += xz[(size_t)(row - 3 + j) * 3072 + c] * cw[c * 4 + j];
  }
  float sg = 1.0f / (1.0f + expf(-acc));
  float val = acc * sg;
  xc[idx] = val;
  xcb[idx] = f2bu(val);
}

// ---- per (b,l): dt transform, closed-form rank-1 NS gamma, u' = gamma*dt*x ----
__global__ __launch_bounds__(256) void precompute_kernel(const float* __restrict__ xdbl,
                                                         float* __restrict__ dtbuf,
                                                         const float* __restrict__ xconv,
                                                         const float* __restrict__ dtb,
                                                         float* __restrict__ ubuf,
                                                         float* __restrict__ kqbuf) {
  int row = blockIdx.x;
  int t = threadIdx.x;
  const float* xr = xdbl + (size_t)row * 80;
  float nk = 0.0f;
#pragma unroll
  for (int n = 0; n < 16; n++) { float kv = xr[48 + n]; nk += kv * kv; }
  float dtf[6], u0[6];
  float nupart = 0.0f;
#pragma unroll
  for (int i = 0; i < 6; i++) {
    int d = i * 256 + t;
    float draw = dtbuf[(size_t)row * D_INNER + d] + dtb[d];
    float sg = 1.0f / (1.0f + expf(-draw));
    float dv = sg / (1.0f + sg * nk);
    dtf[i] = dv;
    float u = dv * xconv[(size_t)row * D_INNER + d];
    u0[i] = u;
    nupart += u * u;
  }
  __shared__ float red[4];
  float v = nupart;
#pragma unroll
  for (int off = 32; off > 0; off >>= 1) v += __shfl_xor(v, off);
  if ((t & 63) == 0) red[t >> 6] = v;
  __syncthreads();
  float nu = red[0] + red[1] + red[2] + red[3];
  float p = nu * nk;
  float s = sqrtf(p) + 1e-7f;
  float tt = p / (s * s);
  float gamma = (3.4445f + tt * (-4.7750f + 2.0315f * tt)) / s;
#pragma unroll
  for (int i = 0; i < 6; i++) {
    int d = i * 256 + t;
    dtbuf[(size_t)row * D_INNER + d] = dtf[i];
    ubuf[(size_t)row * D_INNER + d] = gamma * u0[i];
  }
  if (t < 16) {
    kqbuf[(size_t)row * 32 + t] = xr[48 + t];       // k
    kqbuf[(size_t)row * 32 + 16 + t] = xr[64 + t];  // q
  }
}

// ================= segmented scan =================
// phase 1: per chunk from zero state -> cv, ch, g, r
__global__ __launch_bounds__(64) void scan_phase1(const float* __restrict__ ubuf,
                                                  const float* __restrict__ dtbuf,
                                                  const float* __restrict__ kqbuf,
                                                  float* __restrict__ cvp,
                                                  float* __restrict__ chp,
                                                  float* __restrict__ gp,
                                                  float* __restrict__ rp) {
  __shared__ float u_s[2][32][16];
  __shared__ float dt_s[2][32][16];
  __shared__ __align__(16) float kq_s[2][32][32];
  const int t = threadIdx.x;
  const int nq = t & 3, dloc = t >> 2;
  const int b = blockIdx.x / (96 * CCH);
  const int rem = blockIdx.x % (96 * CCH);
  const int d0 = (rem / CCH) * 16;
  const int c = rem % CCH;
  const int tbase = c * CLEN;
  const size_t ub = (size_t)b * LSEQ * D_INNER + d0;
  const float* kqb = kqbuf + (size_t)b * LSEQ * 32;
  const int scol = t & 15, srow0 = t >> 4;
  const int krow0 = t >> 3, kcol = (t & 7) * 4;
  float pu[8], pd[8];
  f32x4 pk[4];
  auto prefetch = [&](int t0) {
#pragma unroll
    for (int i = 0; i < 8; i++) {
      size_t off = ub + (size_t)(t0 + srow0 + 4 * i) * D_INNER + scol;
      pu[i] = ubuf[off];
      pd[i] = dtbuf[off];
    }
#pragma unroll
    for (int i = 0; i < 4; i++)
      pk[i] = *(const f32x4*)(kqb + (size_t)(t0 + krow0 + 8 * i) * 32 + kcol);
  };
  auto writelds = [&](int bi) {
#pragma unroll
    for (int i = 0; i < 8; i++) {
      u_s[bi][srow0 + 4 * i][scol] = pu[i];
      dt_s[bi][srow0 + 4 * i][scol] = pd[i];
    }
#pragma unroll
    for (int i = 0; i < 4; i++)
      *(f32x4*)&kq_s[bi][krow0 + 8 * i][kcol] = pk[i];
  };
  f32x4 v = {0.f, 0.f, 0.f, 0.f}, h = {0.f, 0.f, 0.f, 0.f};
  f32x4 g = {0.f, 0.f, 0.f, 0.f}, r = {1.f, 1.f, 1.f, 1.f};
  float bt = 0.9f;
  prefetch(tbase);
  writelds(0);
  int buf = 0;
  for (int t0 = 0; t0 < CLEN; t0 += 32) {
    const bool more = (t0 + 32 < CLEN);
    if (more) prefetch(tbase + t0 + 32);
#pragma unroll 4
    for (int s = 0; s < 32; s++) {
      float u = u_s[buf][s][dloc];
      float dtf = dt_s[buf][s][dloc];
      f32x4 kv = *(const f32x4*)&kq_s[buf][s][nq * 4];
#pragma unroll
      for (int j = 0; j < 4; j++) {
        float kj = kv[j];
        v[j] = fmaf(0.9f, v[j], u * kj);
        float a = fmaf(-dtf * kj, kj, 1.0f);
        h[j] = fmaf(a, h[j], v[j]);
        r[j] *= a;
        g[j] = fmaf(a, g[j], bt);
      }
      bt *= 0.9f;
    }
    if (more) writelds(buf ^ 1);
    buf ^= 1;
  }
  size_t o = (((size_t)b * CCH + c) * D_INNER + d0 + dloc) * 16 + nq * 4;
  *(f32x4*)(cvp + o) = v;
  *(f32x4*)(chp + o) = h;
  *(f32x4*)(gp + o) = g;
  *(f32x4*)(rp + o) = r;
}

// phase 2: compose chunk transfers -> per-chunk initial state, in-place over g/r
__global__ __launch_bounds__(256) void scan_phase2(const float* __restrict__ cvp,
                                                   const float* __restrict__ chp,
                                                   float* __restrict__ gp,
                                                   float* __restrict__ rp) {
  int i = blockIdx.x * 256 + threadIdx.x;  // 49152 = 2*1536*16
  int b = i / (D_INNER * 16);
  int rem = i % (D_INNER * 16);
  float v0 = 0.f, h0 = 0.f;
#pragma unroll
  for (int c = 0; c < CCH; c++) {
    size_t o = ((size_t)(b * CCH + c)) * (D_INNER * 16) + rem;
    float cv = cvp[o], ch = chp[o], gg = gp[o], rr = rp[o];
    gp[o] = v0;
    rp[o] = h0;
    float v0n = fmaf(BETA_CL, v0, cv);
    float h0n = fmaf(gg, v0, fmaf(rr, h0, ch));
    v0 = v0n;
    h0 = h0n;
  }
}

// phase 3: per chunk from composed state, emit y
__global__ __launch_bounds__(64) void scan_phase3(const float* __restrict__ ubuf,
                                                  const float* __restrict__ dtbuf,
                                                  const float* __restrict__ kqbuf,
                                                  const float* __restrict__ gp,
                                                  const float* __restrict__ rp,
                                                  float* __restrict__ ybuf) {
  __shared__ float u_s[2][32][16];
  __shared__ float dt_s[2][32][16];
  __shared__ __align__(16) float kq_s[2][32][32];
  const int t = threadIdx.x;
  const int nq = t & 3, dloc = t >> 2;
  const int b = blockIdx.x / (96 * CCH);
  const int rem = blockIdx.x % (96 * CCH);
  const int d0 = (rem / CCH) * 16;
  const int c = rem % CCH;
  const int tbase = c * CLEN;
  const size_t ub = (size_t)b * LSEQ * D_INNER + d0;
  const float* kqb = kqbuf + (size_t)b * LSEQ * 32;
  float* y_p = ybuf + (size_t)b * LSEQ * D_INNER + d0 + dloc;
  const int scol = t & 15, srow0 = t >> 4;
  const int krow0 = t >> 3, kcol = (t & 7) * 4;
  float pu[8], pd[8];
  f32x4 pk[4];
  auto prefetch = [&](int t0) {
#pragma unroll
    for (int i = 0; i < 8; i++) {
      size_t off = ub + (size_t)(t0 + srow0 + 4 * i) * D_INNER + scol;
      pu[i] = ubuf[off];
      pd[i] = dtbuf[off];
    }
#pragma unroll
    for (int i = 0; i < 4; i++)
      pk[i] = *(const f32x4*)(kqb + (size_t)(t0 + krow0 + 8 * i) * 32 + kcol);
  };
  auto writelds = [&](int bi) {
#pragma unroll
    for (int i = 0; i < 8; i++) {
      u_s[bi][srow0 + 4 * i][scol] = pu[i];
      dt_s[bi][srow0 + 4 * i][scol] = pd[i];
    }
#pragma unroll
    for (int i = 0; i < 4; i++)
      *(f32x4*)&kq_s[bi][krow0 + 8 * i][kcol] = pk[i];
  };
  size_t so = (((size_t)b * CCH + c) * D_INNER + d0 + dloc) * 16 + nq * 4;
  f32x4 v = *(const f32x4*)(gp + so);
  f32x4 h = *(const f32x4*)(rp + so);
  prefetch(tbase);
  writelds(0);
  int buf = 0;
  for (int t0 = 0; t0 < CLEN; t0 += 32) {
    const bool more = (t0 + 32 < CLEN);
    if (more) prefetch(tbase + t0 + 32);
#pragma unroll 4
    for (int s = 0; s < 32; s++) {
      float u = u_s[buf][s][dloc];
      float dtf = dt_s[buf][s][dloc];
      f32x4 kv = *(const f32x4*)&kq_s[buf][s][nq * 4];
      f32x4 qv = *(const f32x4*)&kq_s[buf][s][16 + nq * 4];
      float yp = 0.0f;
#pragma unroll
      for (int j = 0; j < 4; j++) {
        float kj = kv[j];
        v[j] = fmaf(0.9f, v[j], u * kj);
        float dA = fmaf(-dtf * kj, kj, 1.0f);
        h[j] = fmaf(dA, h[j], v[j]);
        yp = fmaf(h[j], qv[j], yp);
      }
      yp += __shfl_xor(yp, 1);
      yp += __shfl_xor(yp, 2);
      if (nq == 0) y_p[(size_t)(tbase + t0 + s) * D_INNER] = yp;
    }
    if (more) writelds(buf ^ 1);
    buf ^= 1;
  }
}

// ---- gate: ygb = bf16((y_scan + D*xconv) * silu(z)) ----
__global__ __launch_bounds__(256) void gate_kernel(const float* __restrict__ ybuf,
                                                   const float* __restrict__ xconv,
                                                   const float* __restrict__ xz,
                                                   const float* __restrict__ Dp,
                                                   unsigned short* __restrict__ ygb) {
  int idx = blockIdx.x * 256 + threadIdx.x;
  if (idx >= NROWS * D_INNER) return;
  int c = idx % D_INNER;
  int row = idx / D_INNER;
  float z = xz[(size_t)row * 3072 + 1536 + c];
  float sz = z / (1.0f + expf(-z));
  ygb[idx] = f2bu((ybuf[idx] + Dp[c] * xconv[idx]) * sz);
}

extern "C" void kernel_launch(void* const* d_in, const int* in_sizes, int n_in,
                              void* d_out, int out_size, void* d_ws, size_t ws_size,
                              hipStream_t stream) {
  const float* hidden = (const float*)d_in[0];
  const float* w_in   = (const float*)d_in[1];
  const float* conv_w = (const float*)d_in[2];
  const float* conv_b = (const float*)d_in[3];
  const float* w_x    = (const float*)d_in[4];
  const float* w_dt   = (const float*)d_in[5];
  const float* b_dt   = (const float*)d_in[6];
  const float* w_out  = (const float*)d_in[7];
  const float* Dp     = (const float*)d_in[8];

  float* ws    = (float*)d_ws;
  float* xz    = ws;                                  // 2048*3072
  float* xconv = xz + (size_t)NROWS * 3072;           // 2048*1536
  float* xdbl  = xconv + (size_t)NROWS * D_INNER;     // 2048*80
  float* dtbuf = xdbl + (size_t)NROWS * 80;           // 2048*1536
  float* ubuf  = dtbuf + (size_t)NROWS * D_INNER;     // 2048*1536
  float* kqbuf = ubuf + (size_t)NROWS * D_INNER;      // 2048*32
  float* ybuf  = kqbuf + (size_t)NROWS * 32;          // 2048*1536
  const size_t PL = (size_t)NB * CCH * D_INNER * 16;  // 393216 per plane
  float* cvp   = ybuf + (size_t)NROWS * D_INNER;
  float* chp   = cvp + PL;
  float* gp    = chp + PL;
  float* rp    = gp + PL;
  // bf16 region (after 20676608 floats = 82.7 MB)
  unsigned short* bfr = (unsigned short*)(rp + PL);
  unsigned short* hbf = bfr;                          // 1572864
  unsigned short* wib = hbf + 1572864;                // 2359296
  unsigned short* wxb = wib + 2359296;                // 122880
  unsigned short* wdb = wxb + 122880;                 // 73728
  unsigned short* wob = wdb + 73728;                  // 1179648
  unsigned short* xcb = wob + 1179648;                // 3145728
  unsigned short* ygb = xcb + 3145728;                // 3145728

  dim3 blk(256);
  // zero-init split-K atomic targets
  hipMemsetAsync(xdbl, 0, (size_t)NROWS * 80 * 4, stream);
  hipMemsetAsync(d_out, 0, (size_t)NROWS * 768 * 4, stream);

  // 0. one-shot bf16 conversion of static operands
  cvt5_kernel<<<dim3(CVT_TOTAL / 256), blk, 0, stream>>>(hidden, w_in, w_x, w_dt, w_out,
                                                         hbf, wib, wxb, wdb, wob);
  // 1. in_proj: xz = hidden @ W_in^T  (2048 x 3072, K=768)
  gemm_bt<false, false><<<dim3(48, 32, 1), blk, 0, stream>>>(hbf, wib, xz, 2048, 3072, 768,
                                                             768, 768, 3072, 768);
  // 2. causal conv + SiLU (fp32 + bf16 outputs)
  conv_silu_kernel<<<dim3(12288), blk, 0, stream>>>(xz, conv_w, conv_b, xconv, xcb);
  // 3. x_proj: split-K=8, atomic
  gemm_bt<false, true><<<dim3(2, 32, 8), blk, 0, stream>>>(xcb, wxb, xdbl, 2048, 80, 1536,
                                                           1536, 1536, 80, 192);
  // 4. dt_head: K=48, fp32-A path
  gemm_bt<true, false><<<dim3(24, 32, 1), blk, 0, stream>>>(xdbl, wdb, dtbuf, 2048, 1536, 48,
                                                            80, 48, 1536, 48);
  // 5. precompute dt-final, gamma, u', k, q
  precompute_kernel<<<dim3(NROWS), blk, 0, stream>>>(xdbl, dtbuf, xconv, b_dt, ubuf, kqbuf);
  // 6. segmented scan: 3 phases
  scan_phase1<<<dim3(NB * 96 * CCH), dim3(64), 0, stream>>>(ubuf, dtbuf, kqbuf, cvp, chp, gp, rp);
  scan_phase2<<<dim3(192), blk, 0, stream>>>(cvp, chp, gp, rp);
  scan_phase3<<<dim3(NB * 96 * CCH), dim3(64), 0, stream>>>(ubuf, dtbuf, kqbuf, gp, rp, ybuf);
  // 7. gate -> bf16
  gate_kernel<<<dim3(12288), blk, 0, stream>>>(ybuf, xconv, xz, Dp, ygb);
  // 8. out_proj: split-K=4, atomic -> FP32 d_out
  gemm_bt<false, true><<<dim3(12, 32, 4), blk, 0, stream>>>(ygb, wob, (float*)d_out, 2048, 768,
                                                            1536, 1536, 1536, 768, 384);
}

// Round 11
// 220.484 us; speedup vs baseline: 3.3104x; 1.0876x over previous
//
#include <hip/hip_runtime.h>

#define D_MODEL 768
#define D_STATE 16
#define D_INNER 1536
#define DT_RANK 48
#define NB 2
#define LSEQ 1024
#define NROWS (NB * LSEQ)
#define CCH 8                  // chunks over L
#define CLEN (LSEQ / CCH)      // 128 steps per chunk
#define BETA_CL 1.3900845e-06f // 0.9^128

typedef __attribute__((ext_vector_type(4))) float f32x4;
typedef __attribute__((ext_vector_type(8))) short s16x8;
typedef __attribute__((ext_vector_type(8))) unsigned short u16x8;

__device__ __forceinline__ unsigned short f2bu(float f) {
  unsigned int x = __builtin_bit_cast(unsigned int, f);
  x += 0x7fffu + ((x >> 16) & 1u);
  return (unsigned short)(x >> 16);
}

// ---- one-shot: cvt 5 static operands to bf16 + zero split-K atomic targets ----
// cvt segments (8-elem groups): hidden 196608 | w_in 294912 | w_x 15360 | w_dt 9216 | w_out 147456
#define CVT_TOTAL 663552
#define Z1_GROUPS 20480   // xdbl: 163840 floats
#define Z2_GROUPS 196608  // d_out: 1572864 floats
__global__ __launch_bounds__(256) void cvt5z_kernel(const float* __restrict__ s0,
                                                    const float* __restrict__ s1,
                                                    const float* __restrict__ s2,
                                                    const float* __restrict__ s3,
                                                    const float* __restrict__ s4,
                                                    unsigned short* __restrict__ d0,
                                                    unsigned short* __restrict__ d1,
                                                    unsigned short* __restrict__ d2,
                                                    unsigned short* __restrict__ d3,
                                                    unsigned short* __restrict__ d4,
                                                    float* __restrict__ z1,
                                                    float* __restrict__ z2) {
  int g = blockIdx.x * 256 + threadIdx.x;
  if (g >= CVT_TOTAL) {
    int zg = g - CVT_TOTAL;
    f32x4 zero = {0.f, 0.f, 0.f, 0.f};
    if (zg < Z1_GROUPS) {
      *(f32x4*)(z1 + zg * 8) = zero;
      *(f32x4*)(z1 + zg * 8 + 4) = zero;
    } else if (zg < Z1_GROUPS + Z2_GROUPS) {
      int i = (zg - Z1_GROUPS) * 8;
      *(f32x4*)(z2 + i) = zero;
      *(f32x4*)(z2 + i + 4) = zero;
    }
    return;
  }
  const float* s;
  unsigned short* d;
  int base;
  if (g < 196608)      { s = s0; d = d0; base = 0; }
  else if (g < 491520) { s = s1; d = d1; base = 196608; }
  else if (g < 506880) { s = s2; d = d2; base = 491520; }
  else if (g < 516096) { s = s3; d = d3; base = 506880; }
  else                 { s = s4; d = d4; base = 516096; }
  int i = (g - base) * 8;
  f32x4 a = *(const f32x4*)(s + i);
  f32x4 b = *(const f32x4*)(s + i + 4);
  u16x8 o;
#pragma unroll
  for (int j = 0; j < 4; j++) { o[j] = f2bu(a[j]); o[4 + j] = f2bu(b[j]); }
  *(u16x8*)(d + i) = o;
}

// ---- 128x128 GEMM, bf16 in, fp32 accum. REQUIRES M%128==0, N%128==0, kseg%32==0 ----
// 4 waves, each 64x64 (4x4 16x16 frags, 16 MFMA / K32-iter). Double-buffered LDS.
template <bool ATOMIC>
__global__ __launch_bounds__(256) void gemm128(const unsigned short* __restrict__ A,
                                               const unsigned short* __restrict__ B,
                                               float* __restrict__ C, int K,
                                               int lda, int ldb, int ldc, int kseg_len) {
  __shared__ __align__(16) unsigned short As[2][128][40];
  __shared__ __align__(16) unsigned short Bs[2][128][40];
  const int m0 = blockIdx.y * 128, n0 = blockIdx.x * 128;
  const int kbeg = blockIdx.z * kseg_len;
  const int kend = kbeg + kseg_len;
  const int t = threadIdx.x;
  const int wave = t >> 6, lane = t & 63;
  const int wm = wave >> 1, wn = wave & 1;
  const int quad = lane >> 4, l16 = lane & 15;
  const int arow = t >> 1, kh = (t & 1) * 16;
  const unsigned short* Ap = A + (size_t)(m0 + arow) * lda + kh;
  const unsigned short* Bp = B + (size_t)(n0 + arow) * ldb + kh;

  u16x8 ra0, ra1, rb0, rb1;
  auto pref = [&](int k0) {
    ra0 = *(const u16x8*)(Ap + k0);
    ra1 = *(const u16x8*)(Ap + k0 + 8);
    rb0 = *(const u16x8*)(Bp + k0);
    rb1 = *(const u16x8*)(Bp + k0 + 8);
  };
  auto tolds = [&](int bi) {
    *(u16x8*)&As[bi][arow][kh] = ra0;
    *(u16x8*)&As[bi][arow][kh + 8] = ra1;
    *(u16x8*)&Bs[bi][arow][kh] = rb0;
    *(u16x8*)&Bs[bi][arow][kh + 8] = rb1;
  };

  f32x4 acc[4][4] = {};
  pref(kbeg);
  tolds(0);
  __syncthreads();
  int buf = 0;
  for (int k0 = kbeg; k0 < kend; k0 += 32) {
    const bool more = (k0 + 32 < kend);
    if (more) pref(k0 + 32);  // global loads in flight during MFMA
    s16x8 af[4], bf[4];
#pragma unroll
    for (int i = 0; i < 4; i++) {
      af[i] = *(const s16x8*)&As[buf][wm * 64 + i * 16 + l16][quad * 8];
      bf[i] = *(const s16x8*)&Bs[buf][wn * 64 + i * 16 + l16][quad * 8];
    }
#pragma unroll
    for (int mi = 0; mi < 4; mi++)
#pragma unroll
      for (int ni = 0; ni < 4; ni++)
        acc[mi][ni] = __builtin_amdgcn_mfma_f32_16x16x32_bf16(af[mi], bf[ni], acc[mi][ni], 0, 0, 0);
    if (more) tolds(buf ^ 1);
    __syncthreads();
    buf ^= 1;
  }
#pragma unroll
  for (int mi = 0; mi < 4; mi++)
#pragma unroll
    for (int ni = 0; ni < 4; ni++)
#pragma unroll
      for (int r = 0; r < 4; r++) {
        int row = m0 + wm * 64 + mi * 16 + quad * 4 + r;
        int col = n0 + wn * 64 + ni * 16 + l16;
        if constexpr (ATOMIC)
          atomicAdd(&C[(size_t)row * ldc + col], acc[mi][ni][r]);
        else
          C[(size_t)row * ldc + col] = acc[mi][ni][r];
      }
}

// ---- 64x64 GEMM (bounds-checked) for x_proj / dt_head ----
template <bool AF32, bool ATOMIC>
__global__ __launch_bounds__(256) void gemm_bt(const void* __restrict__ Av,
                                               const unsigned short* __restrict__ B,
                                               float* __restrict__ C, int M, int N, int K,
                                               int lda, int ldb, int ldc, int kseg_len) {
  __shared__ __align__(16) unsigned short As[2][64][40];
  __shared__ __align__(16) unsigned short Bs[2][64][40];
  const int m0 = blockIdx.y * 64, n0 = blockIdx.x * 64;
  const int kbeg = blockIdx.z * kseg_len;
  const int kend = (kbeg + kseg_len < K) ? (kbeg + kseg_len) : K;
  const int t = threadIdx.x;
  const int wave = t >> 6, lane = t & 63;
  const int wm = wave >> 1, wn = wave & 1;
  const int quad = lane >> 4, l16 = lane & 15;
  const int srow = t >> 2;
  const int kseg = (t & 3) * 8;
  const bool va = (m0 + srow) < M, vb = (n0 + srow) < N;
  const float* Af = (const float*)Av;
  const unsigned short* Ab = (const unsigned short*)Av;
  const unsigned short* Bp = B + (size_t)(n0 + srow) * ldb;

  f32x4 ra0, ra1;
  u16x8 rab, rbb;
  auto pref = [&](int k0) {
    const int kk = k0 + kseg;
    const int krem = kend - kk;
    if constexpr (AF32) {
      const float* Ap = Af + (size_t)(m0 + srow) * lda + kk;
      if (va && krem >= 8) {
        ra0 = *(const f32x4*)Ap;
        ra1 = *(const f32x4*)(Ap + 4);
      } else {
#pragma unroll
        for (int j = 0; j < 4; j++) {
          ra0[j] = (va && j < krem) ? Ap[j] : 0.0f;
          ra1[j] = (va && j + 4 < krem) ? Ap[j + 4] : 0.0f;
        }
      }
    } else {
      const unsigned short* Ap = Ab + (size_t)(m0 + srow) * lda + kk;
      if (va && krem >= 8) {
        rab = *(const u16x8*)Ap;
      } else {
#pragma unroll
        for (int j = 0; j < 8; j++) rab[j] = (va && j < krem) ? Ap[j] : (unsigned short)0;
      }
    }
    if (vb && krem >= 8) {
      rbb = *(const u16x8*)(Bp + kk);
    } else {
#pragma unroll
      for (int j = 0; j < 8; j++) rbb[j] = (vb && j < krem) ? Bp[kk + j] : (unsigned short)0;
    }
  };
  auto tolds = [&](int bi) {
    if constexpr (AF32) {
      u16x8 oa;
#pragma unroll
      for (int j = 0; j < 4; j++) { oa[j] = f2bu(ra0[j]); oa[4 + j] = f2bu(ra1[j]); }
      *(u16x8*)&As[bi][srow][kseg] = oa;
    } else {
      *(u16x8*)&As[bi][srow][kseg] = rab;
    }
    *(u16x8*)&Bs[bi][srow][kseg] = rbb;
  };

  f32x4 acc[2][2] = {};
  pref(kbeg);
  tolds(0);
  __syncthreads();
  int buf = 0;
  for (int k0 = kbeg; k0 < kend; k0 += 32) {
    const bool more = (k0 + 32 < kend);
    if (more) pref(k0 + 32);
    s16x8 a0 = *(const s16x8*)&As[buf][wm * 32 + l16][quad * 8];
    s16x8 a1 = *(const s16x8*)&As[buf][wm * 32 + 16 + l16][quad * 8];
    s16x8 b0 = *(const s16x8*)&Bs[buf][wn * 32 + l16][quad * 8];
    s16x8 b1 = *(const s16x8*)&Bs[buf][wn * 32 + 16 + l16][quad * 8];
    acc[0][0] = __builtin_amdgcn_mfma_f32_16x16x32_bf16(a0, b0, acc[0][0], 0, 0, 0);
    acc[0][1] = __builtin_amdgcn_mfma_f32_16x16x32_bf16(a0, b1, acc[0][1], 0, 0, 0);
    acc[1][0] = __builtin_amdgcn_mfma_f32_16x16x32_bf16(a1, b0, acc[1][0], 0, 0, 0);
    acc[1][1] = __builtin_amdgcn_mfma_f32_16x16x32_bf16(a1, b1, acc[1][1], 0, 0, 0);
    if (more) tolds(buf ^ 1);
    __syncthreads();
    buf ^= 1;
  }
#pragma unroll
  for (int mi = 0; mi < 2; mi++)
#pragma unroll
    for (int ni = 0; ni < 2; ni++)
#pragma unroll
      for (int r = 0; r < 4; r++) {
        int row = m0 + wm * 32 + mi * 16 + quad * 4 + r;
        int col = n0 + wn * 32 + ni * 16 + l16;
        if (row < M && col < N) {
          if constexpr (ATOMIC)
            atomicAdd(&C[(size_t)row * ldc + col], acc[mi][ni][r]);
          else
            C[(size_t)row * ldc + col] = acc[mi][ni][r];
        }
      }
}

// ---- causal depthwise conv (width 4) + SiLU; emits fp32 + bf16 copies ----
__global__ __launch_bounds__(256) void conv_silu_kernel(const float* __restrict__ xz,
                                                        const float* __restrict__ cw,
                                                        const float* __restrict__ cb,
                                                        float* __restrict__ xc,
                                                        unsigned short* __restrict__ xcb) {
  int idx = blockIdx.x * 256 + threadIdx.x;
  if (idx >= NROWS * D_INNER) return;
  int c = idx % D_INNER;
  int row = idx / D_INNER;
  int l = row & (LSEQ - 1);
  float acc = cb[c];
#pragma unroll
  for (int j = 0; j < 4; j++) {
    int dl = l - 3 + j;
    if (dl >= 0) acc += xz[(size_t)(row - 3 + j) * 3072 + c] * cw[c * 4 + j];
  }
  float sg = 1.0f / (1.0f + expf(-acc));
  float val = acc * sg;
  xc[idx] = val;
  xcb[idx] = f2bu(val);
}

// ---- per (b,l): dt transform, closed-form rank-1 NS gamma, u' = gamma*dt*x ----
__global__ __launch_bounds__(256) void precompute_kernel(const float* __restrict__ xdbl,
                                                         float* __restrict__ dtbuf,
                                                         const float* __restrict__ xconv,
                                                         const float* __restrict__ dtb,
                                                         float* __restrict__ ubuf,
                                                         float* __restrict__ kqbuf) {
  int row = blockIdx.x;
  int t = threadIdx.x;
  const float* xr = xdbl + (size_t)row * 80;
  float nk = 0.0f;
#pragma unroll
  for (int n = 0; n < 16; n++) { float kv = xr[48 + n]; nk += kv * kv; }
  float dtf[6], u0[6];
  float nupart = 0.0f;
#pragma unroll
  for (int i = 0; i < 6; i++) {
    int d = i * 256 + t;
    float draw = dtbuf[(size_t)row * D_INNER + d] + dtb[d];
    float sg = 1.0f / (1.0f + expf(-draw));
    float dv = sg / (1.0f + sg * nk);
    dtf[i] = dv;
    float u = dv * xconv[(size_t)row * D_INNER + d];
    u0[i] = u;
    nupart += u * u;
  }
  __shared__ float red[4];
  float v = nupart;
#pragma unroll
  for (int off = 32; off > 0; off >>= 1) v += __shfl_xor(v, off);
  if ((t & 63) == 0) red[t >> 6] = v;
  __syncthreads();
  float nu = red[0] + red[1] + red[2] + red[3];
  float p = nu * nk;
  float s = sqrtf(p) + 1e-7f;
  float tt = p / (s * s);
  float gamma = (3.4445f + tt * (-4.7750f + 2.0315f * tt)) / s;
#pragma unroll
  for (int i = 0; i < 6; i++) {
    int d = i * 256 + t;
    dtbuf[(size_t)row * D_INNER + d] = dtf[i];
    ubuf[(size_t)row * D_INNER + d] = gamma * u0[i];
  }
  if (t < 16) {
    kqbuf[(size_t)row * 32 + t] = xr[48 + t];       // k
    kqbuf[(size_t)row * 32 + 16 + t] = xr[64 + t];  // q
  }
}

// ================= segmented scan =================
__global__ __launch_bounds__(64) void scan_phase1(const float* __restrict__ ubuf,
                                                  const float* __restrict__ dtbuf,
                                                  const float* __restrict__ kqbuf,
                                                  float* __restrict__ cvp,
                                                  float* __restrict__ chp,
                                                  float* __restrict__ gp,
                                                  float* __restrict__ rp) {
  __shared__ float u_s[2][32][16];
  __shared__ float dt_s[2][32][16];
  __shared__ __align__(16) float kq_s[2][32][32];
  const int t = threadIdx.x;
  const int nq = t & 3, dloc = t >> 2;
  const int b = blockIdx.x / (96 * CCH);
  const int rem = blockIdx.x % (96 * CCH);
  const int d0 = (rem / CCH) * 16;
  const int c = rem % CCH;
  const int tbase = c * CLEN;
  const size_t ub = (size_t)b * LSEQ * D_INNER + d0;
  const float* kqb = kqbuf + (size_t)b * LSEQ * 32;
  const int scol = t & 15, srow0 = t >> 4;
  const int krow0 = t >> 3, kcol = (t & 7) * 4;
  float pu[8], pd[8];
  f32x4 pk[4];
  auto prefetch = [&](int t0) {
#pragma unroll
    for (int i = 0; i < 8; i++) {
      size_t off = ub + (size_t)(t0 + srow0 + 4 * i) * D_INNER + scol;
      pu[i] = ubuf[off];
      pd[i] = dtbuf[off];
    }
#pragma unroll
    for (int i = 0; i < 4; i++)
      pk[i] = *(const f32x4*)(kqb + (size_t)(t0 + krow0 + 8 * i) * 32 + kcol);
  };
  auto writelds = [&](int bi) {
#pragma unroll
    for (int i = 0; i < 8; i++) {
      u_s[bi][srow0 + 4 * i][scol] = pu[i];
      dt_s[bi][srow0 + 4 * i][scol] = pd[i];
    }
#pragma unroll
    for (int i = 0; i < 4; i++)
      *(f32x4*)&kq_s[bi][krow0 + 8 * i][kcol] = pk[i];
  };
  f32x4 v = {0.f, 0.f, 0.f, 0.f}, h = {0.f, 0.f, 0.f, 0.f};
  f32x4 g = {0.f, 0.f, 0.f, 0.f}, r = {1.f, 1.f, 1.f, 1.f};
  float bt = 0.9f;
  prefetch(tbase);
  writelds(0);
  int buf = 0;
  for (int t0 = 0; t0 < CLEN; t0 += 32) {
    const bool more = (t0 + 32 < CLEN);
    if (more) prefetch(tbase + t0 + 32);
#pragma unroll 4
    for (int s = 0; s < 32; s++) {
      float u = u_s[buf][s][dloc];
      float dtf = dt_s[buf][s][dloc];
      f32x4 kv = *(const f32x4*)&kq_s[buf][s][nq * 4];
#pragma unroll
      for (int j = 0; j < 4; j++) {
        float kj = kv[j];
        v[j] = fmaf(0.9f, v[j], u * kj);
        float a = fmaf(-dtf * kj, kj, 1.0f);
        h[j] = fmaf(a, h[j], v[j]);
        r[j] *= a;
        g[j] = fmaf(a, g[j], bt);
      }
      bt *= 0.9f;
    }
    if (more) writelds(buf ^ 1);
    buf ^= 1;
  }
  size_t o = (((size_t)b * CCH + c) * D_INNER + d0 + dloc) * 16 + nq * 4;
  *(f32x4*)(cvp + o) = v;
  *(f32x4*)(chp + o) = h;
  *(f32x4*)(gp + o) = g;
  *(f32x4*)(rp + o) = r;
}

__global__ __launch_bounds__(256) void scan_phase2(const float* __restrict__ cvp,
                                                   const float* __restrict__ chp,
                                                   float* __restrict__ gp,
                                                   float* __restrict__ rp) {
  int i = blockIdx.x * 256 + threadIdx.x;  // 49152 = 2*1536*16
  int b = i / (D_INNER * 16);
  int rem = i % (D_INNER * 16);
  float v0 = 0.f, h0 = 0.f;
#pragma unroll
  for (int c = 0; c < CCH; c++) {
    size_t o = ((size_t)(b * CCH + c)) * (D_INNER * 16) + rem;
    float cv = cvp[o], ch = chp[o], gg = gp[o], rr = rp[o];
    gp[o] = v0;
    rp[o] = h0;
    float v0n = fmaf(BETA_CL, v0, cv);
    float h0n = fmaf(gg, v0, fmaf(rr, h0, ch));
    v0 = v0n;
    h0 = h0n;
  }
}

__global__ __launch_bounds__(64) void scan_phase3(const float* __restrict__ ubuf,
                                                  const float* __restrict__ dtbuf,
                                                  const float* __restrict__ kqbuf,
                                                  const float* __restrict__ gp,
                                                  const float* __restrict__ rp,
                                                  float* __restrict__ ybuf) {
  __shared__ float u_s[2][32][16];
  __shared__ float dt_s[2][32][16];
  __shared__ __align__(16) float kq_s[2][32][32];
  const int t = threadIdx.x;
  const int nq = t & 3, dloc = t >> 2;
  const int b = blockIdx.x / (96 * CCH);
  const int rem = blockIdx.x % (96 * CCH);
  const int d0 = (rem / CCH) * 16;
  const int c = rem % CCH;
  const int tbase = c * CLEN;
  const size_t ub = (size_t)b * LSEQ * D_INNER + d0;
  const float* kqb = kqbuf + (size_t)b * LSEQ * 32;
  float* y_p = ybuf + (size_t)b * LSEQ * D_INNER + d0 + dloc;
  const int scol = t & 15, srow0 = t >> 4;
  const int krow0 = t >> 3, kcol = (t & 7) * 4;
  float pu[8], pd[8];
  f32x4 pk[4];
  auto prefetch = [&](int t0) {
#pragma unroll
    for (int i = 0; i < 8; i++) {
      size_t off = ub + (size_t)(t0 + srow0 + 4 * i) * D_INNER + scol;
      pu[i] = ubuf[off];
      pd[i] = dtbuf[off];
    }
#pragma unroll
    for (int i = 0; i < 4; i++)
      pk[i] = *(const f32x4*)(kqb + (size_t)(t0 + krow0 + 8 * i) * 32 + kcol);
  };
  auto writelds = [&](int bi) {
#pragma unroll
    for (int i = 0; i < 8; i++) {
      u_s[bi][srow0 + 4 * i][scol] = pu[i];
      dt_s[bi][srow0 + 4 * i][scol] = pd[i];
    }
#pragma unroll
    for (int i = 0; i < 4; i++)
      *(f32x4*)&kq_s[bi][krow0 + 8 * i][kcol] = pk[i];
  };
  size_t so = (((size_t)b * CCH + c) * D_INNER + d0 + dloc) * 16 + nq * 4;
  f32x4 v = *(const f32x4*)(gp + so);
  f32x4 h = *(const f32x4*)(rp + so);
  prefetch(tbase);
  writelds(0);
  int buf = 0;
  for (int t0 = 0; t0 < CLEN; t0 += 32) {
    const bool more = (t0 + 32 < CLEN);
    if (more) prefetch(tbase + t0 + 32);
#pragma unroll 4
    for (int s = 0; s < 32; s++) {
      float u = u_s[buf][s][dloc];
      float dtf = dt_s[buf][s][dloc];
      f32x4 kv = *(const f32x4*)&kq_s[buf][s][nq * 4];
      f32x4 qv = *(const f32x4*)&kq_s[buf][s][16 + nq * 4];
      float yp = 0.0f;
#pragma unroll
      for (int j = 0; j < 4; j++) {
        float kj = kv[j];
        v[j] = fmaf(0.9f, v[j], u * kj);
        float dA = fmaf(-dtf * kj, kj, 1.0f);
        h[j] = fmaf(dA, h[j], v[j]);
        yp = fmaf(h[j], qv[j], yp);
      }
      yp += __shfl_xor(yp, 1);
      yp += __shfl_xor(yp, 2);
      if (nq == 0) y_p[(size_t)(tbase + t0 + s) * D_INNER] = yp;
    }
    if (more) writelds(buf ^ 1);
    buf ^= 1;
  }
}

// ---- gate: ygb = bf16((y_scan + D*xconv) * silu(z)) ----
__global__ __launch_bounds__(256) void gate_kernel(const float* __restrict__ ybuf,
                                                   const float* __restrict__ xconv,
                                                   const float* __restrict__ xz,
                                                   const float* __restrict__ Dp,
                                                   unsigned short* __restrict__ ygb) {
  int idx = blockIdx.x * 256 + threadIdx.x;
  if (idx >= NROWS * D_INNER) return;
  int c = idx % D_INNER;
  int row = idx / D_INNER;
  float z = xz[(size_t)row * 3072 + 1536 + c];
  float sz = z / (1.0f + expf(-z));
  ygb[idx] = f2bu((ybuf[idx] + Dp[c] * xconv[idx]) * sz);
}

extern "C" void kernel_launch(void* const* d_in, const int* in_sizes, int n_in,
                              void* d_out, int out_size, void* d_ws, size_t ws_size,
                              hipStream_t stream) {
  const float* hidden = (const float*)d_in[0];
  const float* w_in   = (const float*)d_in[1];
  const float* conv_w = (const float*)d_in[2];
  const float* conv_b = (const float*)d_in[3];
  const float* w_x    = (const float*)d_in[4];
  const float* w_dt   = (const float*)d_in[5];
  const float* b_dt   = (const float*)d_in[6];
  const float* w_out  = (const float*)d_in[7];
  const float* Dp     = (const float*)d_in[8];

  float* ws    = (float*)d_ws;
  float* xz    = ws;                                  // 2048*3072
  float* xconv = xz + (size_t)NROWS * 3072;           // 2048*1536
  float* xdbl  = xconv + (size_t)NROWS * D_INNER;     // 2048*80
  float* dtbuf = xdbl + (size_t)NROWS * 80;           // 2048*1536
  float* ubuf  = dtbuf + (size_t)NROWS * D_INNER;     // 2048*1536
  float* kqbuf = ubuf + (size_t)NROWS * D_INNER;      // 2048*32
  float* ybuf  = kqbuf + (size_t)NROWS * 32;          // 2048*1536
  const size_t PL = (size_t)NB * CCH * D_INNER * 16;  // 393216 per plane
  float* cvp   = ybuf + (size_t)NROWS * D_INNER;
  float* chp   = cvp + PL;
  float* gp    = chp + PL;
  float* rp    = gp + PL;
  unsigned short* bfr = (unsigned short*)(rp + PL);
  unsigned short* hbf = bfr;                          // 1572864
  unsigned short* wib = hbf + 1572864;                // 2359296
  unsigned short* wxb = wib + 2359296;                // 122880
  unsigned short* wdb = wxb + 122880;                 // 73728
  unsigned short* wob = wdb + 73728;                  // 1179648
  unsigned short* xcb = wob + 1179648;                // 3145728
  unsigned short* ygb = xcb + 3145728;                // 3145728

  dim3 blk(256);
  // 0. cvt static operands to bf16 + zero xdbl/d_out (split-K atomic targets)
  cvt5z_kernel<<<dim3((CVT_TOTAL + Z1_GROUPS + Z2_GROUPS) / 256), blk, 0, stream>>>(
      hidden, w_in, w_x, w_dt, w_out, hbf, wib, wxb, wdb, wob, xdbl, (float*)d_out);
  // 1. in_proj: 128x128 tile (2048 x 3072, K=768)
  gemm128<false><<<dim3(24, 16, 1), blk, 0, stream>>>(hbf, wib, xz, 768, 768, 768, 3072, 768);
  // 2. causal conv + SiLU (fp32 + bf16 outputs)
  conv_silu_kernel<<<dim3(12288), blk, 0, stream>>>(xz, conv_w, conv_b, xconv, xcb);
  // 3. x_proj: 64-tile split-K=8, atomic (2048 x 80, K=1536)
  gemm_bt<false, true><<<dim3(2, 32, 8), blk, 0, stream>>>(xcb, wxb, xdbl, 2048, 80, 1536,
                                                           1536, 1536, 80, 192);
  // 4. dt_head: 64-tile, fp32-A (2048 x 1536, K=48)
  gemm_bt<true, false><<<dim3(24, 32, 1), blk, 0, stream>>>(xdbl, wdb, dtbuf, 2048, 1536, 48,
                                                            80, 48, 1536, 48);
  // 5. precompute dt-final, gamma, u', k, q
  precompute_kernel<<<dim3(NROWS), blk, 0, stream>>>(xdbl, dtbuf, xconv, b_dt, ubuf, kqbuf);
  // 6. segmented scan: 3 phases
  scan_phase1<<<dim3(NB * 96 * CCH), dim3(64), 0, stream>>>(ubuf, dtbuf, kqbuf, cvp, chp, gp, rp);
  scan_phase2<<<dim3(192), blk, 0, stream>>>(cvp, chp, gp, rp);
  scan_phase3<<<dim3(NB * 96 * CCH), dim3(64), 0, stream>>>(ubuf, dtbuf, kqbuf, gp, rp, ybuf);
  // 7. gate -> bf16
  gate_kernel<<<dim3(12288), blk, 0, stream>>>(ybuf, xconv, xz, Dp, ygb);
  // 8. out_proj: 128x128 split-K=2, atomic -> FP32 d_out (2048 x 768, K=1536)
  gemm128<true><<<dim3(6, 16, 2), blk, 0, stream>>>(ygb, wob, (float*)d_out, 1536,
                                                    1536, 1536, 768, 768);
}